// Round 10
// baseline (468.525 us; speedup 1.0000x reference)
//
#include <hip/hip_runtime.h>
#include <hip/hip_bf16.h>
#include <cstddef>

#define NN 50000
#define EE 800000
#define NB ((NN + 255) / 256)

typedef __attribute__((ext_vector_type(8))) short short8;
typedef __attribute__((ext_vector_type(4))) float f32x4;

__device__ __forceinline__ float leaky(float x) { return x >= 0.f ? x : 0.2f * x; }
__device__ __forceinline__ float bf2f(unsigned short u) {
  return __uint_as_float(((unsigned int)u) << 16);
}
__device__ __forceinline__ float bflo(unsigned int v) { return __uint_as_float(v << 16); }
__device__ __forceinline__ float bfhi(unsigned int v) { return __uint_as_float(v & 0xFFFF0000u); }
__device__ __forceinline__ unsigned short f2bf(float f) {
  __hip_bfloat16 b = __float2bfloat16(f);
  return __builtin_bit_cast(unsigned short, b);
}
__device__ __forceinline__ float selh(float4 v, int h) {
  float a = (h & 1) ? v.y : v.x;
  float b = (h & 1) ? v.w : v.z;
  return (h & 2) ? b : a;
}
__device__ __forceinline__ void accum8(float a, uint4 v, float* acc) {
  acc[0] += a * bflo(v.x); acc[1] += a * bfhi(v.x);
  acc[2] += a * bflo(v.y); acc[3] += a * bfhi(v.y);
  acc[4] += a * bflo(v.z); acc[5] += a * bfhi(v.z);
  acc[6] += a * bflo(v.w); acc[7] += a * bfhi(v.w);
}

// ==== bf16 MFMA GEMM + fused attention-logit epilogue =======================
__global__ __launch_bounds__(256) void gemm_bf16_k(const unsigned short* __restrict__ A,
                                                   const unsigned short* __restrict__ Bt,
                                                   unsigned short* __restrict__ Cb,
                                                   int K, int Nfull,
                                                   const float* __restrict__ a_s,
                                                   const float* __restrict__ a_d,
                                                   float* __restrict__ als,
                                                   float* __restrict__ ald,
                                                   float* __restrict__ selfex) {
  __shared__ __align__(16) unsigned short As[128 * 40];
  __shared__ __align__(16) unsigned short Bs[64 * 40];
  const int tid = threadIdx.x;
  const int lane = tid & 63;
  const int w = tid >> 6;
  const int bm = blockIdx.x * 128;
  const int bn = blockIdx.y * 64;
  const int quad = lane >> 4;
  const int l16 = lane & 15;
  f32x4 acc[2][4] = {};
  for (int kc = 0; kc < K; kc += 32) {
    {
      int row = tid >> 2, seg = tid & 3;
      int sr = bm + row; if (sr >= NN) sr = NN - 1;
      *(uint4*)&As[row * 40 + seg * 8] = *(const uint4*)(A + (size_t)sr * K + kc + seg * 8);
      row = (tid + 256) >> 2; seg = (tid + 256) & 3;
      sr = bm + row; if (sr >= NN) sr = NN - 1;
      *(uint4*)&As[row * 40 + seg * 8] = *(const uint4*)(A + (size_t)sr * K + kc + seg * 8);
      int n = tid >> 2; seg = tid & 3;
      *(uint4*)&Bs[n * 40 + seg * 8] = *(const uint4*)(Bt + (size_t)(bn + n) * K + kc + seg * 8);
    }
    __syncthreads();
    short8 afr0 = *(const short8*)&As[(w * 32 + l16) * 40 + quad * 8];
    short8 afr1 = *(const short8*)&As[(w * 32 + 16 + l16) * 40 + quad * 8];
#pragma unroll
    for (int nt = 0; nt < 4; ++nt) {
      short8 bfr = *(const short8*)&Bs[(nt * 16 + l16) * 40 + quad * 8];
      acc[0][nt] = __builtin_amdgcn_mfma_f32_16x16x32_bf16(afr0, bfr, acc[0][nt], 0, 0, 0);
      acc[1][nt] = __builtin_amdgcn_mfma_f32_16x16x32_bf16(afr1, bfr, acc[1][nt], 0, 0, 0);
    }
    __syncthreads();
  }
  const int head = bn >> 6;
  const int Hmul = Nfull >> 6;
  float vs[2][4] = {};
  float vd[2][4] = {};
#pragma unroll
  for (int nt = 0; nt < 4; ++nt) {
    const float asv = a_s[head * 64 + nt * 16 + l16];
    const float adv = a_d[head * 64 + nt * 16 + l16];
#pragma unroll
    for (int mt = 0; mt < 2; ++mt)
#pragma unroll
      for (int reg = 0; reg < 4; ++reg) {
        unsigned short c = f2bf(acc[mt][nt][reg]);
        int r = bm + w * 32 + mt * 16 + quad * 4 + reg;
        if (r < NN) Cb[(size_t)r * Nfull + bn + nt * 16 + l16] = c;
        float hv = bf2f(c);
        vs[mt][reg] += hv * asv;
        vd[mt][reg] += hv * adv;
      }
  }
#pragma unroll
  for (int off = 1; off < 16; off <<= 1) {
#pragma unroll
    for (int mt = 0; mt < 2; ++mt)
#pragma unroll
      for (int reg = 0; reg < 4; ++reg) {
        vs[mt][reg] += __shfl_xor(vs[mt][reg], off, 64);
        vd[mt][reg] += __shfl_xor(vd[mt][reg], off, 64);
      }
  }
  if (l16 == 0) {
#pragma unroll
    for (int mt = 0; mt < 2; ++mt)
#pragma unroll
      for (int reg = 0; reg < 4; ++reg) {
        int r = bm + w * 32 + mt * 16 + quad * 4 + reg;
        if (r < NN) {
          als[(size_t)r * Hmul + head] = vs[mt][reg];
          ald[(size_t)r * Hmul + head] = vd[mt][reg];
          selfex[(size_t)r * Hmul + head] = __expf(leaky(vs[mt][reg] + vd[mt][reg]));
        }
      }
  }
}

// ================= CSR build (topology is layer-invariant) ==================
__global__ __launch_bounds__(256) void hist_k(const int* __restrict__ ei, int* deg) {
  int i = blockIdx.x * 256 + threadIdx.x;
  if (i < EE) atomicAdd(&deg[ei[EE + i]], 1);
}

__global__ __launch_bounds__(256) void scan1_k(const int* __restrict__ deg,
                                               int* __restrict__ incl,
                                               int* __restrict__ partial) {
  __shared__ int s[256];
  int t = threadIdx.x;
  int i = blockIdx.x * 256 + t;
  int v = (i < NN) ? deg[i] : 0;
  s[t] = v;
  __syncthreads();
  for (int off = 1; off < 256; off <<= 1) {
    int u = (t >= off) ? s[t - off] : 0;
    __syncthreads();
    s[t] += u;
    __syncthreads();
  }
  if (i < NN) incl[i] = s[t];
  if (t == 255) partial[blockIdx.x] = s[255];
}

__global__ void scan2_k(int* __restrict__ partial) {
  __shared__ int s[256];
  int t = threadIdx.x;
  int v = (t < NB) ? partial[t] : 0;
  s[t] = v;
  __syncthreads();
  for (int off = 1; off < 256; off <<= 1) {
    int u = (t >= off) ? s[t - off] : 0;
    __syncthreads();
    s[t] += u;
    __syncthreads();
  }
  if (t < NB) partial[t] = s[t] - v;  // exclusive
}

__global__ __launch_bounds__(256) void scan3_k(const int* __restrict__ deg,
                                               const int* __restrict__ incl,
                                               const int* __restrict__ partial,
                                               int* __restrict__ rowptr,
                                               int* __restrict__ cursor) {
  int i = blockIdx.x * 256 + threadIdx.x;
  if (i >= NN) return;
  int r = partial[blockIdx.x] + incl[i] - deg[i];
  rowptr[i] = r;
  cursor[i] = r;
}

__global__ __launch_bounds__(256) void scatter_k(const int* __restrict__ ei,
                                                 int* __restrict__ cursor,
                                                 int* __restrict__ csr_src,
                                                 int* __restrict__ csr_dst) {
  int i = blockIdx.x * 256 + threadIdx.x;
  if (i >= EE) return;
  int d = ei[EE + i];
  int p = atomicAdd(&cursor[d], 1);
  csr_src[p] = ei[i];
  csr_dst[p] = d;
}

// ====== per-CSR-slot unnormalized exp, AoS float4 (H=4) =====================
__global__ __launch_bounds__(256) void edge_exp4_k(const int* __restrict__ csr_src,
                                                   const int* __restrict__ csr_dst,
                                                   const float* __restrict__ als,
                                                   const float* __restrict__ ald,
                                                   float4* __restrict__ ex4) {
  int i = blockIdx.x * 256 + threadIdx.x;
  if (i >= EE) return;
  int s = csr_src[i], d = csr_dst[i];
  const float4 as4 = *(const float4*)(als + (size_t)s * 4);
  const float4 ad4 = *(const float4*)(ald + (size_t)d * 4);
  float4 e;
  e.x = __expf(leaky(as4.x + ad4.x));
  e.y = __expf(leaky(as4.y + ad4.y));
  e.z = __expf(leaky(as4.z + ad4.z));
  e.w = __expf(leaky(as4.w + ad4.w));
  ex4[i] = e;
}

__global__ __launch_bounds__(256) void edge_exp1_k(const int* __restrict__ csr_src,
                                                   const int* __restrict__ csr_dst,
                                                   const float* __restrict__ als,
                                                   const float* __restrict__ ald,
                                                   float* __restrict__ ex1) {
  int i = blockIdx.x * 256 + threadIdx.x;
  if (i >= EE) return;
  ex1[i] = __expf(leaky(als[csr_src[i]] + ald[csr_dst[i]]));
}

// ====== gather-aggregate + inline den-sum, H=4: wave/dst ====================
// 4 edge-slots x 16 lanes x 32B; 4-edge unroll per slot => 16 edges in flight
// per wave (index loads batched, then ex loads, then row loads). Zero atomics.
__global__ __launch_bounds__(256) void aggr4c_k(const int* __restrict__ rowptr,
                                                const int* __restrict__ deg,
                                                const int* __restrict__ csr_src,
                                                const float4* __restrict__ ex4,
                                                const float* __restrict__ selfex,
                                                const uint4* __restrict__ hb4,
                                                const float* __restrict__ bias,
                                                uint4* __restrict__ out4) {
  const int dst = blockIdx.x * 4 + (threadIdx.x >> 6);
  const int lane = threadIdx.x & 63;
  const int slot = lane >> 4;
  const int l16 = lane & 15;
  const int head = l16 >> 2;
  const int rs = rowptr[dst];
  const int dg = deg[dst];

  float acc[16] = {};
  float dsum = 0.f;
  if (slot == 0) {  // self-loop (unnormalized)
    float a = selfex[dst * 4 + head];
    dsum += a;
    uint4 v0 = hb4[(size_t)dst * 32 + l16 * 2];
    uint4 v1 = hb4[(size_t)dst * 32 + l16 * 2 + 1];
    accum8(a, v0, acc);
    accum8(a, v1, acc + 8);
  }
  int j = slot;
  for (; j + 12 < dg; j += 16) {
    int s0 = csr_src[rs + j];
    int s1 = csr_src[rs + j + 4];
    int s2 = csr_src[rs + j + 8];
    int s3 = csr_src[rs + j + 12];
    float4 av0 = ex4[rs + j];
    float4 av1 = ex4[rs + j + 4];
    float4 av2 = ex4[rs + j + 8];
    float4 av3 = ex4[rs + j + 12];
    uint4 va0 = hb4[(size_t)s0 * 32 + l16 * 2];
    uint4 vb0 = hb4[(size_t)s0 * 32 + l16 * 2 + 1];
    uint4 va1 = hb4[(size_t)s1 * 32 + l16 * 2];
    uint4 vb1 = hb4[(size_t)s1 * 32 + l16 * 2 + 1];
    uint4 va2 = hb4[(size_t)s2 * 32 + l16 * 2];
    uint4 vb2 = hb4[(size_t)s2 * 32 + l16 * 2 + 1];
    uint4 va3 = hb4[(size_t)s3 * 32 + l16 * 2];
    uint4 vb3 = hb4[(size_t)s3 * 32 + l16 * 2 + 1];
    float a0 = selh(av0, head);
    float a1 = selh(av1, head);
    float a2 = selh(av2, head);
    float a3 = selh(av3, head);
    dsum += (a0 + a1) + (a2 + a3);
    accum8(a0, va0, acc); accum8(a0, vb0, acc + 8);
    accum8(a1, va1, acc); accum8(a1, vb1, acc + 8);
    accum8(a2, va2, acc); accum8(a2, vb2, acc + 8);
    accum8(a3, va3, acc); accum8(a3, vb3, acc + 8);
  }
  for (; j < dg; j += 4) {
    int s0 = csr_src[rs + j];
    float4 av0 = ex4[rs + j];
    uint4 va0 = hb4[(size_t)s0 * 32 + l16 * 2];
    uint4 vb0 = hb4[(size_t)s0 * 32 + l16 * 2 + 1];
    float a0 = selh(av0, head);
    dsum += a0;
    accum8(a0, va0, acc);
    accum8(a0, vb0, acc + 8);
  }
#pragma unroll
  for (int k = 0; k < 16; ++k) {
    acc[k] += __shfl_xor(acc[k], 16, 64);
    acc[k] += __shfl_xor(acc[k], 32, 64);
  }
  dsum += __shfl_xor(dsum, 16, 64);
  dsum += __shfl_xor(dsum, 32, 64);
  if (slot == 0) {  // channels [l16*16, l16*16+16), relu (both H=4 layers)
    const float inv = 1.f / (dsum + 1e-16f);
    const float* bz = bias + l16 * 16;
    uint4 o0, o1;
    float c0, c1;
    c0 = fmaxf(acc[0] * inv + bz[0], 0.f);   c1 = fmaxf(acc[1] * inv + bz[1], 0.f);
    o0.x = ((unsigned int)f2bf(c1) << 16) | f2bf(c0);
    c0 = fmaxf(acc[2] * inv + bz[2], 0.f);   c1 = fmaxf(acc[3] * inv + bz[3], 0.f);
    o0.y = ((unsigned int)f2bf(c1) << 16) | f2bf(c0);
    c0 = fmaxf(acc[4] * inv + bz[4], 0.f);   c1 = fmaxf(acc[5] * inv + bz[5], 0.f);
    o0.z = ((unsigned int)f2bf(c1) << 16) | f2bf(c0);
    c0 = fmaxf(acc[6] * inv + bz[6], 0.f);   c1 = fmaxf(acc[7] * inv + bz[7], 0.f);
    o0.w = ((unsigned int)f2bf(c1) << 16) | f2bf(c0);
    c0 = fmaxf(acc[8] * inv + bz[8], 0.f);   c1 = fmaxf(acc[9] * inv + bz[9], 0.f);
    o1.x = ((unsigned int)f2bf(c1) << 16) | f2bf(c0);
    c0 = fmaxf(acc[10] * inv + bz[10], 0.f); c1 = fmaxf(acc[11] * inv + bz[11], 0.f);
    o1.y = ((unsigned int)f2bf(c1) << 16) | f2bf(c0);
    c0 = fmaxf(acc[12] * inv + bz[12], 0.f); c1 = fmaxf(acc[13] * inv + bz[13], 0.f);
    o1.z = ((unsigned int)f2bf(c1) << 16) | f2bf(c0);
    c0 = fmaxf(acc[14] * inv + bz[14], 0.f); c1 = fmaxf(acc[15] * inv + bz[15], 0.f);
    o1.w = ((unsigned int)f2bf(c1) << 16) | f2bf(c0);
    out4[(size_t)dst * 32 + l16 * 2] = o0;
    out4[(size_t)dst * 32 + l16 * 2 + 1] = o1;
  }
}

// ====== gather-aggregate + inline den-sum, H=1: wave/dst, 8 slots x 8 lanes ==
// 2-iteration unroll => 16 edges in flight per wave.
__global__ __launch_bounds__(256) void aggr1c_k(const int* __restrict__ rowptr,
                                                const int* __restrict__ deg,
                                                const int* __restrict__ csr_src,
                                                const float* __restrict__ ex1,
                                                const float* __restrict__ selfex,
                                                const uint4* __restrict__ hb4,
                                                const float* __restrict__ bias,
                                                float* __restrict__ out) {
  const int dst = blockIdx.x * 4 + (threadIdx.x >> 6);
  const int lane = threadIdx.x & 63;
  const int slot = lane >> 3;
  const int c8 = lane & 7;
  const int rs = rowptr[dst];
  const int dg = deg[dst];

  float acc[8] = {};
  float dsum = 0.f;
  if (slot == 0) {
    float a = selfex[dst];
    dsum += a;
    uint4 v = hb4[(size_t)dst * 8 + c8];
    accum8(a, v, acc);
  }
  int j = slot;
  for (; j + 8 < dg; j += 16) {
    int s0 = csr_src[rs + j];
    int s1 = csr_src[rs + j + 8];
    float a0 = ex1[rs + j];
    float a1 = ex1[rs + j + 8];
    uint4 v0 = hb4[(size_t)s0 * 8 + c8];
    uint4 v1 = hb4[(size_t)s1 * 8 + c8];
    dsum += a0 + a1;
    accum8(a0, v0, acc);
    accum8(a1, v1, acc);
  }
  for (; j < dg; j += 8) {
    int s = csr_src[rs + j];
    float a = ex1[rs + j];
    uint4 v = hb4[(size_t)s * 8 + c8];
    dsum += a;
    accum8(a, v, acc);
  }
#pragma unroll
  for (int k = 0; k < 8; ++k) {
    acc[k] += __shfl_xor(acc[k], 8, 64);
    acc[k] += __shfl_xor(acc[k], 16, 64);
    acc[k] += __shfl_xor(acc[k], 32, 64);
  }
  dsum += __shfl_xor(dsum, 8, 64);
  dsum += __shfl_xor(dsum, 16, 64);
  dsum += __shfl_xor(dsum, 32, 64);
  if (slot == 0) {  // no relu on layer 2; fp32 out
    const float inv = 1.f / (dsum + 1e-16f);
    const float4 bz0 = *(const float4*)(bias + c8 * 8);
    const float4 bz1 = *(const float4*)(bias + c8 * 8 + 4);
    float4 o0 = make_float4(acc[0] * inv + bz0.x, acc[1] * inv + bz0.y,
                            acc[2] * inv + bz0.z, acc[3] * inv + bz0.w);
    float4 o1 = make_float4(acc[4] * inv + bz1.x, acc[5] * inv + bz1.y,
                            acc[6] * inv + bz1.z, acc[7] * inv + bz1.w);
    *(float4*)(out + (size_t)dst * 64 + c8 * 8) = o0;
    *(float4*)(out + (size_t)dst * 64 + c8 * 8 + 4) = o1;
  }
}

// ---- fused prep: x->bf16 cast (blocks 0..12499) + 3 weight transposes ------
__global__ __launch_bounds__(256) void prep_k(const float2* __restrict__ x2,
                                              unsigned int* __restrict__ xb_u,
                                              const float* __restrict__ W0,
                                              unsigned short* __restrict__ W0t,
                                              const float* __restrict__ W1,
                                              unsigned short* __restrict__ W1t,
                                              const float* __restrict__ W2,
                                              unsigned short* __restrict__ W2t) {
  int bid = blockIdx.x;
  int tid = threadIdx.x;
  if (bid < 12500) {  // castx: NN*128/2 = 3.2M uints
    int i = bid * 256 + tid;
    float2 v = x2[i];
    xb_u[i] = ((unsigned int)f2bf(v.y) << 16) | f2bf(v.x);
    return;
  }
  int r = (bid - 12500) * 256 + tid;
  if (r < 32768) {            // W0t[256][128] <- W0[128][256]
    int n = r >> 7, k = r & 127;
    W0t[n * 128 + k] = f2bf(W0[k * 256 + n]);
  } else if (r < 98304) {     // W1t[256][256] <- W1[256][256]
    int rr = r - 32768;
    int n = rr >> 8, k = rr & 255;
    W1t[n * 256 + k] = f2bf(W1[k * 256 + n]);
  } else {                    // W2t[64][256] <- W2[256][64]
    int rr = r - 98304;
    int n = rr >> 8, k = rr & 255;
    W2t[n * 256 + k] = f2bf(W2[k * 64 + n]);
  }
}

// ---- colsum + fused head: last block computes the final [1,64] output ------
__global__ __launch_bounds__(256) void colsum_head_k(const float* __restrict__ h2,
                                                     float* __restrict__ g,
                                                     unsigned int* __restrict__ cnt,
                                                     const float* __restrict__ hw,
                                                     const float* __restrict__ hb,
                                                     float* __restrict__ out) {
  __shared__ float s[256];
  __shared__ float sg[64];
  __shared__ unsigned int sdone;
  int tid = threadIdx.x;
  int c = tid & 63, rg = tid >> 6;
  float acc = 0.f;
  for (int n = blockIdx.x * 4 + rg; n < NN; n += gridDim.x * 4)
    acc += h2[n * 64 + c];
  s[tid] = acc;
  __syncthreads();
  if (tid < 64) atomicAdd(&g[c], s[c] + s[64 + c] + s[128 + c] + s[192 + c]);
  __threadfence();
  __syncthreads();
  if (tid == 0) sdone = atomicAdd(cnt, 1);
  __syncthreads();
  if (sdone != gridDim.x - 1) return;
  // last block: all other blocks' g-atomics are complete (fence+counter order)
  if (tid < 64) sg[tid] = atomicAdd(&g[tid], 0.f);  // coherent read
  __syncthreads();
  if (tid < 64) {
    const float invN = 1.0f / (float)NN;
    float a2 = hb[tid];
#pragma unroll 8
    for (int cc = 0; cc < 64; ++cc) a2 += sg[cc] * invN * hw[cc * 64 + tid];
    out[tid] = a2;
  }
}

extern "C" void kernel_launch(void* const* d_in, const int* in_sizes, int n_in,
                              void* d_out, int out_size, void* d_ws, size_t ws_size,
                              hipStream_t stream) {
  const float* x   = (const float*)d_in[0];
  const int*   ei  = (const int*)d_in[1];
  const float* W0  = (const float*)d_in[2];
  const float* a0s = (const float*)d_in[3];
  const float* a0d = (const float*)d_in[4];
  const float* b0  = (const float*)d_in[5];
  const float* W1  = (const float*)d_in[6];
  const float* a1s = (const float*)d_in[7];
  const float* a1d = (const float*)d_in[8];
  const float* b1  = (const float*)d_in[9];
  const float* W2  = (const float*)d_in[10];
  const float* a2s = (const float*)d_in[11];
  const float* a2d = (const float*)d_in[12];
  const float* b2  = (const float*)d_in[13];
  const float* hw  = (const float*)d_in[14];
  const float* hb  = (const float*)d_in[15];
  float* out = (float*)d_out;

  char* w = (char*)d_ws;
  unsigned short* xb   = (unsigned short*)w; w += (size_t)NN * 128 * 2;
  unsigned short* bufG = (unsigned short*)w; w += (size_t)NN * 256 * 2;
  unsigned short* bufA = (unsigned short*)w; w += (size_t)NN * 256 * 2;
  float* bufF = (float*)w;                   w += (size_t)NN * 64 * 4;
  unsigned short* W0t = (unsigned short*)w;  w += 256 * 128 * 2;
  unsigned short* W1t = (unsigned short*)w;  w += 256 * 256 * 2;
  unsigned short* W2t = (unsigned short*)w;  w += 64 * 256 * 2;
  float* als  = (float*)w;    w += (size_t)NN * 4 * 4;
  float* ald  = (float*)w;    w += (size_t)NN * 4 * 4;
  float* sfx  = (float*)w;    w += (size_t)NN * 4 * 4;
  float4* ex4 = (float4*)w;   w += (size_t)EE * 16;  // reused as ex1 plane for H=1
  int* deg     = (int*)w;     w += (size_t)NN * 4;
  int* rowptr  = (int*)w;     w += (size_t)NN * 4;
  int* cursor  = (int*)w;     w += (size_t)NN * 4;
  int* incl    = (int*)w;     w += (size_t)NN * 4;
  int* partial = (int*)w;     w += 256 * 4;
  int* csr_src = (int*)w;     w += (size_t)EE * 4;
  int* csr_dst = (int*)w;     w += (size_t)EE * 4;
  float* g    = (float*)w;    w += 256;           // g[0..63] sums; cnt at g+64

  // ---- CSR build (shared by all 3 layers) ----
  hipMemsetAsync(deg, 0, (size_t)NN * 4, stream);
  hist_k<<<(EE + 255) / 256, 256, 0, stream>>>(ei, deg);
  scan1_k<<<NB, 256, 0, stream>>>(deg, incl, partial);
  scan2_k<<<1, 256, 0, stream>>>(partial);
  scan3_k<<<NB, 256, 0, stream>>>(deg, incl, partial, rowptr, cursor);
  scatter_k<<<(EE + 255) / 256, 256, 0, stream>>>(ei, cursor, csr_src, csr_dst);

  // ---- fused prep: cast + 3 transposes ----
  prep_k<<<12500 + 448, 256, 0, stream>>>((const float2*)x, (unsigned int*)xb,
                                          W0, W0t, W1, W1t, W2, W2t);

  const int GX = (NN + 127) / 128;
  const int GA = NN / 4;   // 12500 exact
  const int GE = EE / 256; // 3125 exact

  auto layer4 = [&](const unsigned short* in, int K, const unsigned short* Wt,
                    const float* a_s, const float* a_d, const float* bias,
                    unsigned short* hbuf, unsigned short* obuf) {
    gemm_bf16_k<<<dim3(GX, 4), 256, 0, stream>>>(in, Wt, hbuf, K, 256,
                                                 a_s, a_d, als, ald, sfx);
    edge_exp4_k<<<GE, 256, 0, stream>>>(csr_src, csr_dst, als, ald, ex4);
    aggr4c_k<<<GA, 256, 0, stream>>>(rowptr, deg, csr_src, ex4, sfx,
                                     (const uint4*)hbuf, bias, (uint4*)obuf);
  };

  // layers 0 and 1 (H=4)
  layer4(xb, 128, W0t, a0s, a0d, b0, bufG, bufA);
  layer4(bufA, 256, W1t, a1s, a1d, b1, bufG, bufA);

  // layer 2 (H=1)
  gemm_bf16_k<<<dim3(GX, 1), 256, 0, stream>>>(bufA, W2t, bufG, 256, 64,
                                               a2s, a2d, als, ald, sfx);
  edge_exp1_k<<<GE, 256, 0, stream>>>(csr_src, csr_dst, als, ald, (float*)ex4);
  aggr1c_k<<<GA, 256, 0, stream>>>(rowptr, deg, csr_src, (const float*)ex4, sfx,
                                   (const uint4*)bufG, b2, bufF);

  // ---- mean + head (fused; g[0..63] sums, counter at g+64) ----
  hipMemsetAsync(g, 0, 68 * 4, stream);
  colsum_head_k<<<256, 256, 0, stream>>>(bufF, g, (unsigned int*)(g + 64), hw, hb, out);
}

// Round 11
// 458.734 us; speedup vs baseline: 1.0213x; 1.0213x over previous
//
#include <hip/hip_runtime.h>
#include <hip/hip_bf16.h>
#include <cstddef>

#define NN 50000
#define EE 800000
#define NB ((NN + 255) / 256)

typedef __attribute__((ext_vector_type(8))) short short8;
typedef __attribute__((ext_vector_type(4))) float f32x4;

__device__ __forceinline__ float leaky(float x) { return x >= 0.f ? x : 0.2f * x; }
__device__ __forceinline__ float bf2f(unsigned short u) {
  return __uint_as_float(((unsigned int)u) << 16);
}
__device__ __forceinline__ float bflo(unsigned int v) { return __uint_as_float(v << 16); }
__device__ __forceinline__ float bfhi(unsigned int v) { return __uint_as_float(v & 0xFFFF0000u); }
__device__ __forceinline__ unsigned short f2bf(float f) {
  __hip_bfloat16 b = __float2bfloat16(f);
  return __builtin_bit_cast(unsigned short, b);
}
__device__ __forceinline__ float selh(float4 v, int h) {
  float a = (h & 1) ? v.y : v.x;
  float b = (h & 1) ? v.w : v.z;
  return (h & 2) ? b : a;
}
__device__ __forceinline__ void accum8(float a, uint4 v, float* acc) {
  acc[0] += a * bflo(v.x); acc[1] += a * bfhi(v.x);
  acc[2] += a * bflo(v.y); acc[3] += a * bfhi(v.y);
  acc[4] += a * bflo(v.z); acc[5] += a * bfhi(v.z);
  acc[6] += a * bflo(v.w); acc[7] += a * bfhi(v.w);
}

// ==== bf16 MFMA GEMM + fused attention-logit epilogue =======================
__global__ __launch_bounds__(256) void gemm_bf16_k(const unsigned short* __restrict__ A,
                                                   const unsigned short* __restrict__ Bt,
                                                   unsigned short* __restrict__ Cb,
                                                   int K, int Nfull,
                                                   const float* __restrict__ a_s,
                                                   const float* __restrict__ a_d,
                                                   float* __restrict__ als,
                                                   float* __restrict__ ald,
                                                   float* __restrict__ selfex) {
  __shared__ __align__(16) unsigned short As[128 * 40];
  __shared__ __align__(16) unsigned short Bs[64 * 40];
  const int tid = threadIdx.x;
  const int lane = tid & 63;
  const int w = tid >> 6;
  const int bm = blockIdx.x * 128;
  const int bn = blockIdx.y * 64;
  const int quad = lane >> 4;
  const int l16 = lane & 15;
  f32x4 acc[2][4] = {};
  for (int kc = 0; kc < K; kc += 32) {
    {
      int row = tid >> 2, seg = tid & 3;
      int sr = bm + row; if (sr >= NN) sr = NN - 1;
      *(uint4*)&As[row * 40 + seg * 8] = *(const uint4*)(A + (size_t)sr * K + kc + seg * 8);
      row = (tid + 256) >> 2; seg = (tid + 256) & 3;
      sr = bm + row; if (sr >= NN) sr = NN - 1;
      *(uint4*)&As[row * 40 + seg * 8] = *(const uint4*)(A + (size_t)sr * K + kc + seg * 8);
      int n = tid >> 2; seg = tid & 3;
      *(uint4*)&Bs[n * 40 + seg * 8] = *(const uint4*)(Bt + (size_t)(bn + n) * K + kc + seg * 8);
    }
    __syncthreads();
    short8 afr0 = *(const short8*)&As[(w * 32 + l16) * 40 + quad * 8];
    short8 afr1 = *(const short8*)&As[(w * 32 + 16 + l16) * 40 + quad * 8];
#pragma unroll
    for (int nt = 0; nt < 4; ++nt) {
      short8 bfr = *(const short8*)&Bs[(nt * 16 + l16) * 40 + quad * 8];
      acc[0][nt] = __builtin_amdgcn_mfma_f32_16x16x32_bf16(afr0, bfr, acc[0][nt], 0, 0, 0);
      acc[1][nt] = __builtin_amdgcn_mfma_f32_16x16x32_bf16(afr1, bfr, acc[1][nt], 0, 0, 0);
    }
    __syncthreads();
  }
  const int head = bn >> 6;
  const int Hmul = Nfull >> 6;
  float vs[2][4] = {};
  float vd[2][4] = {};
#pragma unroll
  for (int nt = 0; nt < 4; ++nt) {
    const float asv = a_s[head * 64 + nt * 16 + l16];
    const float adv = a_d[head * 64 + nt * 16 + l16];
#pragma unroll
    for (int mt = 0; mt < 2; ++mt)
#pragma unroll
      for (int reg = 0; reg < 4; ++reg) {
        unsigned short c = f2bf(acc[mt][nt][reg]);
        int r = bm + w * 32 + mt * 16 + quad * 4 + reg;
        if (r < NN) Cb[(size_t)r * Nfull + bn + nt * 16 + l16] = c;
        float hv = bf2f(c);
        vs[mt][reg] += hv * asv;
        vd[mt][reg] += hv * adv;
      }
  }
#pragma unroll
  for (int off = 1; off < 16; off <<= 1) {
#pragma unroll
    for (int mt = 0; mt < 2; ++mt)
#pragma unroll
      for (int reg = 0; reg < 4; ++reg) {
        vs[mt][reg] += __shfl_xor(vs[mt][reg], off, 64);
        vd[mt][reg] += __shfl_xor(vd[mt][reg], off, 64);
      }
  }
  if (l16 == 0) {
#pragma unroll
    for (int mt = 0; mt < 2; ++mt)
#pragma unroll
      for (int reg = 0; reg < 4; ++reg) {
        int r = bm + w * 32 + mt * 16 + quad * 4 + reg;
        if (r < NN) {
          als[(size_t)r * Hmul + head] = vs[mt][reg];
          ald[(size_t)r * Hmul + head] = vd[mt][reg];
          selfex[(size_t)r * Hmul + head] = __expf(leaky(vs[mt][reg] + vd[mt][reg]));
        }
      }
  }
}

// ================= CSR build (topology is layer-invariant) ==================
__global__ __launch_bounds__(256) void hist_k(const int* __restrict__ ei, int* deg) {
  int i = blockIdx.x * 256 + threadIdx.x;
  if (i < EE) atomicAdd(&deg[ei[EE + i]], 1);
}

__global__ __launch_bounds__(256) void scan1_k(const int* __restrict__ deg,
                                               int* __restrict__ incl,
                                               int* __restrict__ partial) {
  __shared__ int s[256];
  int t = threadIdx.x;
  int i = blockIdx.x * 256 + t;
  int v = (i < NN) ? deg[i] : 0;
  s[t] = v;
  __syncthreads();
  for (int off = 1; off < 256; off <<= 1) {
    int u = (t >= off) ? s[t - off] : 0;
    __syncthreads();
    s[t] += u;
    __syncthreads();
  }
  if (i < NN) incl[i] = s[t];
  if (t == 255) partial[blockIdx.x] = s[255];
}

__global__ void scan2_k(int* __restrict__ partial) {
  __shared__ int s[256];
  int t = threadIdx.x;
  int v = (t < NB) ? partial[t] : 0;
  s[t] = v;
  __syncthreads();
  for (int off = 1; off < 256; off <<= 1) {
    int u = (t >= off) ? s[t - off] : 0;
    __syncthreads();
    s[t] += u;
    __syncthreads();
  }
  if (t < NB) partial[t] = s[t] - v;  // exclusive
}

__global__ __launch_bounds__(256) void scan3_k(const int* __restrict__ deg,
                                               const int* __restrict__ incl,
                                               const int* __restrict__ partial,
                                               int* __restrict__ rowptr,
                                               int* __restrict__ cursor) {
  int i = blockIdx.x * 256 + threadIdx.x;
  if (i >= NN) return;
  int r = partial[blockIdx.x] + incl[i] - deg[i];
  rowptr[i] = r;
  cursor[i] = r;
}

__global__ __launch_bounds__(256) void scatter_k(const int* __restrict__ ei,
                                                 int* __restrict__ cursor,
                                                 int* __restrict__ csr_src,
                                                 int* __restrict__ csr_dst) {
  int i = blockIdx.x * 256 + threadIdx.x;
  if (i >= EE) return;
  int d = ei[EE + i];
  int p = atomicAdd(&cursor[d], 1);
  csr_src[p] = ei[i];
  csr_dst[p] = d;
}

// ====== per-CSR-slot unnormalized exp, AoS float4 (H=4) =====================
__global__ __launch_bounds__(256) void edge_exp4_k(const int* __restrict__ csr_src,
                                                   const int* __restrict__ csr_dst,
                                                   const float* __restrict__ als,
                                                   const float* __restrict__ ald,
                                                   float4* __restrict__ ex4) {
  int i = blockIdx.x * 256 + threadIdx.x;
  if (i >= EE) return;
  int s = csr_src[i], d = csr_dst[i];
  const float4 as4 = *(const float4*)(als + (size_t)s * 4);
  const float4 ad4 = *(const float4*)(ald + (size_t)d * 4);
  float4 e;
  e.x = __expf(leaky(as4.x + ad4.x));
  e.y = __expf(leaky(as4.y + ad4.y));
  e.z = __expf(leaky(as4.z + ad4.z));
  e.w = __expf(leaky(as4.w + ad4.w));
  ex4[i] = e;
}

__global__ __launch_bounds__(256) void edge_exp1_k(const int* __restrict__ csr_src,
                                                   const int* __restrict__ csr_dst,
                                                   const float* __restrict__ als,
                                                   const float* __restrict__ ald,
                                                   float* __restrict__ ex1) {
  int i = blockIdx.x * 256 + threadIdx.x;
  if (i >= EE) return;
  ex1[i] = __expf(leaky(als[csr_src[i]] + ald[csr_dst[i]]));
}

// ====== gather-aggregate + inline den-sum, H=4: wave/dst ====================
// 4 edge-slots x 16 lanes x 32B, 2-edge unroll (round-9 tuning: VGPR 36,
// ~61 us @ 3.7 TB/s; deeper unroll measured worse). Zero atomics.
__global__ __launch_bounds__(256) void aggr4c_k(const int* __restrict__ rowptr,
                                                const int* __restrict__ deg,
                                                const int* __restrict__ csr_src,
                                                const float4* __restrict__ ex4,
                                                const float* __restrict__ selfex,
                                                const uint4* __restrict__ hb4,
                                                const float* __restrict__ bias,
                                                uint4* __restrict__ out4) {
  const int dst = blockIdx.x * 4 + (threadIdx.x >> 6);
  const int lane = threadIdx.x & 63;
  const int slot = lane >> 4;
  const int l16 = lane & 15;
  const int head = l16 >> 2;
  const int rs = rowptr[dst];
  const int dg = deg[dst];

  float acc[16] = {};
  float dsum = 0.f;
  if (slot == 0) {  // self-loop (unnormalized)
    float a = selfex[dst * 4 + head];
    dsum += a;
    uint4 v0 = hb4[(size_t)dst * 32 + l16 * 2];
    uint4 v1 = hb4[(size_t)dst * 32 + l16 * 2 + 1];
    accum8(a, v0, acc);
    accum8(a, v1, acc + 8);
  }
  int j = slot;
  for (; j + 4 < dg; j += 8) {
    int s0 = csr_src[rs + j];
    int s1 = csr_src[rs + j + 4];
    float4 av0 = ex4[rs + j];
    float4 av1 = ex4[rs + j + 4];
    uint4 va0 = hb4[(size_t)s0 * 32 + l16 * 2];
    uint4 vb0 = hb4[(size_t)s0 * 32 + l16 * 2 + 1];
    uint4 va1 = hb4[(size_t)s1 * 32 + l16 * 2];
    uint4 vb1 = hb4[(size_t)s1 * 32 + l16 * 2 + 1];
    float a0 = selh(av0, head);
    float a1 = selh(av1, head);
    dsum += a0 + a1;
    accum8(a0, va0, acc);
    accum8(a0, vb0, acc + 8);
    accum8(a1, va1, acc);
    accum8(a1, vb1, acc + 8);
  }
  for (; j < dg; j += 4) {
    int s0 = csr_src[rs + j];
    float4 av0 = ex4[rs + j];
    uint4 va0 = hb4[(size_t)s0 * 32 + l16 * 2];
    uint4 vb0 = hb4[(size_t)s0 * 32 + l16 * 2 + 1];
    float a0 = selh(av0, head);
    dsum += a0;
    accum8(a0, va0, acc);
    accum8(a0, vb0, acc + 8);
  }
#pragma unroll
  for (int k = 0; k < 16; ++k) {
    acc[k] += __shfl_xor(acc[k], 16, 64);
    acc[k] += __shfl_xor(acc[k], 32, 64);
  }
  dsum += __shfl_xor(dsum, 16, 64);
  dsum += __shfl_xor(dsum, 32, 64);
  if (slot == 0) {  // channels [l16*16, l16*16+16), relu (both H=4 layers)
    const float inv = 1.f / (dsum + 1e-16f);
    const float* bz = bias + l16 * 16;
    uint4 o0, o1;
    float c0, c1;
    c0 = fmaxf(acc[0] * inv + bz[0], 0.f);   c1 = fmaxf(acc[1] * inv + bz[1], 0.f);
    o0.x = ((unsigned int)f2bf(c1) << 16) | f2bf(c0);
    c0 = fmaxf(acc[2] * inv + bz[2], 0.f);   c1 = fmaxf(acc[3] * inv + bz[3], 0.f);
    o0.y = ((unsigned int)f2bf(c1) << 16) | f2bf(c0);
    c0 = fmaxf(acc[4] * inv + bz[4], 0.f);   c1 = fmaxf(acc[5] * inv + bz[5], 0.f);
    o0.z = ((unsigned int)f2bf(c1) << 16) | f2bf(c0);
    c0 = fmaxf(acc[6] * inv + bz[6], 0.f);   c1 = fmaxf(acc[7] * inv + bz[7], 0.f);
    o0.w = ((unsigned int)f2bf(c1) << 16) | f2bf(c0);
    c0 = fmaxf(acc[8] * inv + bz[8], 0.f);   c1 = fmaxf(acc[9] * inv + bz[9], 0.f);
    o1.x = ((unsigned int)f2bf(c1) << 16) | f2bf(c0);
    c0 = fmaxf(acc[10] * inv + bz[10], 0.f); c1 = fmaxf(acc[11] * inv + bz[11], 0.f);
    o1.y = ((unsigned int)f2bf(c1) << 16) | f2bf(c0);
    c0 = fmaxf(acc[12] * inv + bz[12], 0.f); c1 = fmaxf(acc[13] * inv + bz[13], 0.f);
    o1.z = ((unsigned int)f2bf(c1) << 16) | f2bf(c0);
    c0 = fmaxf(acc[14] * inv + bz[14], 0.f); c1 = fmaxf(acc[15] * inv + bz[15], 0.f);
    o1.w = ((unsigned int)f2bf(c1) << 16) | f2bf(c0);
    out4[(size_t)dst * 32 + l16 * 2] = o0;
    out4[(size_t)dst * 32 + l16 * 2 + 1] = o1;
  }
}

// ====== gather-aggregate + inline den-sum, H=1: wave/dst, 8 slots x 8 lanes ==
__global__ __launch_bounds__(256) void aggr1c_k(const int* __restrict__ rowptr,
                                                const int* __restrict__ deg,
                                                const int* __restrict__ csr_src,
                                                const float* __restrict__ ex1,
                                                const float* __restrict__ selfex,
                                                const uint4* __restrict__ hb4,
                                                const float* __restrict__ bias,
                                                float* __restrict__ out) {
  const int dst = blockIdx.x * 4 + (threadIdx.x >> 6);
  const int lane = threadIdx.x & 63;
  const int slot = lane >> 3;
  const int c8 = lane & 7;
  const int rs = rowptr[dst];
  const int dg = deg[dst];

  float acc[8] = {};
  float dsum = 0.f;
  if (slot == 0) {
    float a = selfex[dst];
    dsum += a;
    uint4 v = hb4[(size_t)dst * 8 + c8];
    accum8(a, v, acc);
  }
  for (int j = slot; j < dg; j += 8) {
    int s = csr_src[rs + j];
    float a = ex1[rs + j];
    dsum += a;
    uint4 v = hb4[(size_t)s * 8 + c8];
    accum8(a, v, acc);
  }
#pragma unroll
  for (int k = 0; k < 8; ++k) {
    acc[k] += __shfl_xor(acc[k], 8, 64);
    acc[k] += __shfl_xor(acc[k], 16, 64);
    acc[k] += __shfl_xor(acc[k], 32, 64);
  }
  dsum += __shfl_xor(dsum, 8, 64);
  dsum += __shfl_xor(dsum, 16, 64);
  dsum += __shfl_xor(dsum, 32, 64);
  if (slot == 0) {  // no relu on layer 2; fp32 out
    const float inv = 1.f / (dsum + 1e-16f);
    const float4 bz0 = *(const float4*)(bias + c8 * 8);
    const float4 bz1 = *(const float4*)(bias + c8 * 8 + 4);
    float4 o0 = make_float4(acc[0] * inv + bz0.x, acc[1] * inv + bz0.y,
                            acc[2] * inv + bz0.z, acc[3] * inv + bz0.w);
    float4 o1 = make_float4(acc[4] * inv + bz1.x, acc[5] * inv + bz1.y,
                            acc[6] * inv + bz1.z, acc[7] * inv + bz1.w);
    *(float4*)(out + (size_t)dst * 64 + c8 * 8) = o0;
    *(float4*)(out + (size_t)dst * 64 + c8 * 8 + 4) = o1;
  }
}

// ---- fused prep: x->bf16 cast (blocks 0..12499) + 3 weight transposes ------
__global__ __launch_bounds__(256) void prep_k(const float2* __restrict__ x2,
                                              unsigned int* __restrict__ xb_u,
                                              const float* __restrict__ W0,
                                              unsigned short* __restrict__ W0t,
                                              const float* __restrict__ W1,
                                              unsigned short* __restrict__ W1t,
                                              const float* __restrict__ W2,
                                              unsigned short* __restrict__ W2t) {
  int bid = blockIdx.x;
  int tid = threadIdx.x;
  if (bid < 12500) {  // castx: NN*128/2 = 3.2M uints
    int i = bid * 256 + tid;
    float2 v = x2[i];
    xb_u[i] = ((unsigned int)f2bf(v.y) << 16) | f2bf(v.x);
    return;
  }
  int r = (bid - 12500) * 256 + tid;
  if (r < 32768) {            // W0t[256][128] <- W0[128][256]
    int n = r >> 7, k = r & 127;
    W0t[n * 128 + k] = f2bf(W0[k * 256 + n]);
  } else if (r < 98304) {     // W1t[256][256] <- W1[256][256]
    int rr = r - 32768;
    int n = rr >> 8, k = rr & 255;
    W1t[n * 256 + k] = f2bf(W1[k * 256 + n]);
  } else {                    // W2t[64][256] <- W2[256][64]
    int rr = r - 98304;
    int n = rr >> 8, k = rr & 255;
    W2t[n * 256 + k] = f2bf(W2[k * 64 + n]);
  }
}

// ---- colsum + fused head: last block computes the final [1,64] output ------
__global__ __launch_bounds__(256) void colsum_head_k(const float* __restrict__ h2,
                                                     float* __restrict__ g,
                                                     unsigned int* __restrict__ cnt,
                                                     const float* __restrict__ hw,
                                                     const float* __restrict__ hb,
                                                     float* __restrict__ out) {
  __shared__ float s[256];
  __shared__ float sg[64];
  __shared__ unsigned int sdone;
  int tid = threadIdx.x;
  int c = tid & 63, rg = tid >> 6;
  float acc = 0.f;
  for (int n = blockIdx.x * 4 + rg; n < NN; n += gridDim.x * 4)
    acc += h2[n * 64 + c];
  s[tid] = acc;
  __syncthreads();
  if (tid < 64) atomicAdd(&g[c], s[c] + s[64 + c] + s[128 + c] + s[192 + c]);
  __threadfence();
  __syncthreads();
  if (tid == 0) sdone = atomicAdd(cnt, 1);
  __syncthreads();
  if (sdone != gridDim.x - 1) return;
  // last block: all other blocks' g-atomics are complete (fence+counter order)
  if (tid < 64) sg[tid] = atomicAdd(&g[tid], 0.f);  // coherent read
  __syncthreads();
  if (tid < 64) {
    const float invN = 1.0f / (float)NN;
    float a2 = hb[tid];
#pragma unroll 8
    for (int cc = 0; cc < 64; ++cc) a2 += sg[cc] * invN * hw[cc * 64 + tid];
    out[tid] = a2;
  }
}

extern "C" void kernel_launch(void* const* d_in, const int* in_sizes, int n_in,
                              void* d_out, int out_size, void* d_ws, size_t ws_size,
                              hipStream_t stream) {
  const float* x   = (const float*)d_in[0];
  const int*   ei  = (const int*)d_in[1];
  const float* W0  = (const float*)d_in[2];
  const float* a0s = (const float*)d_in[3];
  const float* a0d = (const float*)d_in[4];
  const float* b0  = (const float*)d_in[5];
  const float* W1  = (const float*)d_in[6];
  const float* a1s = (const float*)d_in[7];
  const float* a1d = (const float*)d_in[8];
  const float* b1  = (const float*)d_in[9];
  const float* W2  = (const float*)d_in[10];
  const float* a2s = (const float*)d_in[11];
  const float* a2d = (const float*)d_in[12];
  const float* b2  = (const float*)d_in[13];
  const float* hw  = (const float*)d_in[14];
  const float* hb  = (const float*)d_in[15];
  float* out = (float*)d_out;

  char* w = (char*)d_ws;
  unsigned short* xb   = (unsigned short*)w; w += (size_t)NN * 128 * 2;
  unsigned short* bufG = (unsigned short*)w; w += (size_t)NN * 256 * 2;
  unsigned short* bufA = (unsigned short*)w; w += (size_t)NN * 256 * 2;
  float* bufF = (float*)w;                   w += (size_t)NN * 64 * 4;
  unsigned short* W0t = (unsigned short*)w;  w += 256 * 128 * 2;
  unsigned short* W1t = (unsigned short*)w;  w += 256 * 256 * 2;
  unsigned short* W2t = (unsigned short*)w;  w += 64 * 256 * 2;
  float* als  = (float*)w;    w += (size_t)NN * 4 * 4;
  float* ald  = (float*)w;    w += (size_t)NN * 4 * 4;
  float* sfx  = (float*)w;    w += (size_t)NN * 4 * 4;
  float4* ex4 = (float4*)w;   w += (size_t)EE * 16;  // reused as ex1 plane for H=1
  int* deg     = (int*)w;     w += (size_t)NN * 4;
  int* rowptr  = (int*)w;     w += (size_t)NN * 4;
  int* cursor  = (int*)w;     w += (size_t)NN * 4;
  int* incl    = (int*)w;     w += (size_t)NN * 4;
  int* partial = (int*)w;     w += 256 * 4;
  int* csr_src = (int*)w;     w += (size_t)EE * 4;
  int* csr_dst = (int*)w;     w += (size_t)EE * 4;
  float* g    = (float*)w;    w += 256;           // g[0..63] sums; cnt at g+64

  // ---- CSR build (shared by all 3 layers) ----
  hipMemsetAsync(deg, 0, (size_t)NN * 4, stream);
  hist_k<<<(EE + 255) / 256, 256, 0, stream>>>(ei, deg);
  scan1_k<<<NB, 256, 0, stream>>>(deg, incl, partial);
  scan2_k<<<1, 256, 0, stream>>>(partial);
  scan3_k<<<NB, 256, 0, stream>>>(deg, incl, partial, rowptr, cursor);
  scatter_k<<<(EE + 255) / 256, 256, 0, stream>>>(ei, cursor, csr_src, csr_dst);

  // ---- fused prep: cast + 3 transposes ----
  prep_k<<<12500 + 448, 256, 0, stream>>>((const float2*)x, (unsigned int*)xb,
                                          W0, W0t, W1, W1t, W2, W2t);

  const int GX = (NN + 127) / 128;
  const int GA = NN / 4;   // 12500 exact
  const int GE = EE / 256; // 3125 exact

  auto layer4 = [&](const unsigned short* in, int K, const unsigned short* Wt,
                    const float* a_s, const float* a_d, const float* bias,
                    unsigned short* hbuf, unsigned short* obuf) {
    gemm_bf16_k<<<dim3(GX, 4), 256, 0, stream>>>(in, Wt, hbuf, K, 256,
                                                 a_s, a_d, als, ald, sfx);
    edge_exp4_k<<<GE, 256, 0, stream>>>(csr_src, csr_dst, als, ald, ex4);
    aggr4c_k<<<GA, 256, 0, stream>>>(rowptr, deg, csr_src, ex4, sfx,
                                     (const uint4*)hbuf, bias, (uint4*)obuf);
  };

  // layers 0 and 1 (H=4)
  layer4(xb, 128, W0t, a0s, a0d, b0, bufG, bufA);
  layer4(bufA, 256, W1t, a1s, a1d, b1, bufG, bufA);

  // layer 2 (H=1)
  gemm_bf16_k<<<dim3(GX, 1), 256, 0, stream>>>(bufA, W2t, bufG, 256, 64,
                                               a2s, a2d, als, ald, sfx);
  edge_exp1_k<<<GE, 256, 0, stream>>>(csr_src, csr_dst, als, ald, (float*)ex4);
  aggr1c_k<<<GA, 256, 0, stream>>>(rowptr, deg, csr_src, (const float*)ex4, sfx,
                                   (const uint4*)bufG, b2, bufF);

  // ---- mean + head (fused; g[0..63] sums, counter at g+64) ----
  hipMemsetAsync(g, 0, 68 * 4, stream);
  colsum_head_k<<<256, 256, 0, stream>>>(bufF, g, (unsigned int*)(g + 64), hw, hb, out);
}

// Round 12
// 440.946 us; speedup vs baseline: 1.0625x; 1.0403x over previous
//
#include <hip/hip_runtime.h>
#include <hip/hip_bf16.h>
#include <cstddef>

#define NN 50000
#define EE 800000
#define NB ((NN + 255) / 256)

typedef __attribute__((ext_vector_type(8))) short short8;
typedef __attribute__((ext_vector_type(4))) float f32x4;

__device__ __forceinline__ float leaky(float x) { return x >= 0.f ? x : 0.2f * x; }
__device__ __forceinline__ float bf2f(unsigned short u) {
  return __uint_as_float(((unsigned int)u) << 16);
}
__device__ __forceinline__ float bflo(unsigned int v) { return __uint_as_float(v << 16); }
__device__ __forceinline__ float bfhi(unsigned int v) { return __uint_as_float(v & 0xFFFF0000u); }
__device__ __forceinline__ unsigned short f2bf(float f) {
  __hip_bfloat16 b = __float2bfloat16(f);
  return __builtin_bit_cast(unsigned short, b);
}
__device__ __forceinline__ void accum8(float a, uint4 v, float* acc) {
  acc[0] += a * bflo(v.x); acc[1] += a * bfhi(v.x);
  acc[2] += a * bflo(v.y); acc[3] += a * bfhi(v.y);
  acc[4] += a * bflo(v.z); acc[5] += a * bfhi(v.z);
  acc[6] += a * bflo(v.w); acc[7] += a * bfhi(v.w);
}

// ==== bf16 MFMA GEMM + fused attention-logit epilogue =======================
__global__ __launch_bounds__(256) void gemm_bf16_k(const unsigned short* __restrict__ A,
                                                   const unsigned short* __restrict__ Bt,
                                                   unsigned short* __restrict__ Cb,
                                                   int K, int Nfull,
                                                   const float* __restrict__ a_s,
                                                   const float* __restrict__ a_d,
                                                   float* __restrict__ als,
                                                   float* __restrict__ ald,
                                                   float* __restrict__ selfex) {
  __shared__ __align__(16) unsigned short As[128 * 40];
  __shared__ __align__(16) unsigned short Bs[64 * 40];
  const int tid = threadIdx.x;
  const int lane = tid & 63;
  const int w = tid >> 6;
  const int bm = blockIdx.x * 128;
  const int bn = blockIdx.y * 64;
  const int quad = lane >> 4;
  const int l16 = lane & 15;
  f32x4 acc[2][4] = {};
  for (int kc = 0; kc < K; kc += 32) {
    {
      int row = tid >> 2, seg = tid & 3;
      int sr = bm + row; if (sr >= NN) sr = NN - 1;
      *(uint4*)&As[row * 40 + seg * 8] = *(const uint4*)(A + (size_t)sr * K + kc + seg * 8);
      row = (tid + 256) >> 2; seg = (tid + 256) & 3;
      sr = bm + row; if (sr >= NN) sr = NN - 1;
      *(uint4*)&As[row * 40 + seg * 8] = *(const uint4*)(A + (size_t)sr * K + kc + seg * 8);
      int n = tid >> 2; seg = tid & 3;
      *(uint4*)&Bs[n * 40 + seg * 8] = *(const uint4*)(Bt + (size_t)(bn + n) * K + kc + seg * 8);
    }
    __syncthreads();
    short8 afr0 = *(const short8*)&As[(w * 32 + l16) * 40 + quad * 8];
    short8 afr1 = *(const short8*)&As[(w * 32 + 16 + l16) * 40 + quad * 8];
#pragma unroll
    for (int nt = 0; nt < 4; ++nt) {
      short8 bfr = *(const short8*)&Bs[(nt * 16 + l16) * 40 + quad * 8];
      acc[0][nt] = __builtin_amdgcn_mfma_f32_16x16x32_bf16(afr0, bfr, acc[0][nt], 0, 0, 0);
      acc[1][nt] = __builtin_amdgcn_mfma_f32_16x16x32_bf16(afr1, bfr, acc[1][nt], 0, 0, 0);
    }
    __syncthreads();
  }
  const int head = bn >> 6;
  const int Hmul = Nfull >> 6;
  float vs[2][4] = {};
  float vd[2][4] = {};
#pragma unroll
  for (int nt = 0; nt < 4; ++nt) {
    const float asv = a_s[head * 64 + nt * 16 + l16];
    const float adv = a_d[head * 64 + nt * 16 + l16];
#pragma unroll
    for (int mt = 0; mt < 2; ++mt)
#pragma unroll
      for (int reg = 0; reg < 4; ++reg) {
        unsigned short c = f2bf(acc[mt][nt][reg]);
        int r = bm + w * 32 + mt * 16 + quad * 4 + reg;
        if (r < NN) Cb[(size_t)r * Nfull + bn + nt * 16 + l16] = c;
        float hv = bf2f(c);
        vs[mt][reg] += hv * asv;
        vd[mt][reg] += hv * adv;
      }
  }
#pragma unroll
  for (int off = 1; off < 16; off <<= 1) {
#pragma unroll
    for (int mt = 0; mt < 2; ++mt)
#pragma unroll
      for (int reg = 0; reg < 4; ++reg) {
        vs[mt][reg] += __shfl_xor(vs[mt][reg], off, 64);
        vd[mt][reg] += __shfl_xor(vd[mt][reg], off, 64);
      }
  }
  if (l16 == 0) {
#pragma unroll
    for (int mt = 0; mt < 2; ++mt)
#pragma unroll
      for (int reg = 0; reg < 4; ++reg) {
        int r = bm + w * 32 + mt * 16 + quad * 4 + reg;
        if (r < NN) {
          als[(size_t)r * Hmul + head] = vs[mt][reg];
          ald[(size_t)r * Hmul + head] = vd[mt][reg];
          selfex[(size_t)r * Hmul + head] = __expf(leaky(vs[mt][reg] + vd[mt][reg]));
        }
      }
  }
}

// ================= CSR build (topology is layer-invariant) ==================
__global__ __launch_bounds__(256) void hist_k(const int* __restrict__ ei, int* deg) {
  int i = blockIdx.x * 256 + threadIdx.x;
  if (i < EE) atomicAdd(&deg[ei[EE + i]], 1);
}

__global__ __launch_bounds__(256) void scan1_k(const int* __restrict__ deg,
                                               int* __restrict__ incl,
                                               int* __restrict__ partial) {
  __shared__ int s[256];
  int t = threadIdx.x;
  int i = blockIdx.x * 256 + t;
  int v = (i < NN) ? deg[i] : 0;
  s[t] = v;
  __syncthreads();
  for (int off = 1; off < 256; off <<= 1) {
    int u = (t >= off) ? s[t - off] : 0;
    __syncthreads();
    s[t] += u;
    __syncthreads();
  }
  if (i < NN) incl[i] = s[t];
  if (t == 255) partial[blockIdx.x] = s[255];
}

__global__ void scan2_k(int* __restrict__ partial) {
  __shared__ int s[256];
  int t = threadIdx.x;
  int v = (t < NB) ? partial[t] : 0;
  s[t] = v;
  __syncthreads();
  for (int off = 1; off < 256; off <<= 1) {
    int u = (t >= off) ? s[t - off] : 0;
    __syncthreads();
    s[t] += u;
    __syncthreads();
  }
  if (t < NB) partial[t] = s[t] - v;  // exclusive
}

__global__ __launch_bounds__(256) void scan3_k(const int* __restrict__ deg,
                                               const int* __restrict__ incl,
                                               const int* __restrict__ partial,
                                               int* __restrict__ rowptr,
                                               int* __restrict__ cursor) {
  int i = blockIdx.x * 256 + threadIdx.x;
  if (i >= NN) return;
  int r = partial[blockIdx.x] + incl[i] - deg[i];
  rowptr[i] = r;
  cursor[i] = r;
}

__global__ __launch_bounds__(256) void scatter_k(const int* __restrict__ ei,
                                                 int* __restrict__ cursor,
                                                 int* __restrict__ csr_src) {
  int i = blockIdx.x * 256 + threadIdx.x;
  if (i >= EE) return;
  int d = ei[EE + i];
  int p = atomicAdd(&cursor[d], 1);
  csr_src[p] = ei[i];
}

// ====== gather-aggregate, inline alpha + inline den-sum, H=4: wave/dst ======
// 4 edge-slots x 16 lanes x 32B, 2-edge unroll. alpha computed inline from the
// L2-resident als table (als load || h-row loads — both depend only on s).
// Zero atomics, no edge-exp staging pass.
__global__ __launch_bounds__(256) void aggr4c_k(const int* __restrict__ rowptr,
                                                const int* __restrict__ deg,
                                                const int* __restrict__ csr_src,
                                                const float* __restrict__ als,
                                                const float* __restrict__ ald,
                                                const float* __restrict__ selfex,
                                                const uint4* __restrict__ hb4,
                                                const float* __restrict__ bias,
                                                uint4* __restrict__ out4) {
  const int dst = blockIdx.x * 4 + (threadIdx.x >> 6);
  const int lane = threadIdx.x & 63;
  const int slot = lane >> 4;
  const int l16 = lane & 15;
  const int head = l16 >> 2;
  const int rs = rowptr[dst];
  const int dg = deg[dst];
  const float aldv = ald[dst * 4 + head];

  float acc[16] = {};
  float dsum = 0.f;
  if (slot == 0) {  // self-loop (unnormalized)
    float a = selfex[dst * 4 + head];
    dsum += a;
    uint4 v0 = hb4[(size_t)dst * 32 + l16 * 2];
    uint4 v1 = hb4[(size_t)dst * 32 + l16 * 2 + 1];
    accum8(a, v0, acc);
    accum8(a, v1, acc + 8);
  }
  int j = slot;
  for (; j + 4 < dg; j += 8) {
    int s0 = csr_src[rs + j];
    int s1 = csr_src[rs + j + 4];
    float e0 = als[s0 * 4 + head];
    float e1 = als[s1 * 4 + head];
    uint4 va0 = hb4[(size_t)s0 * 32 + l16 * 2];
    uint4 vb0 = hb4[(size_t)s0 * 32 + l16 * 2 + 1];
    uint4 va1 = hb4[(size_t)s1 * 32 + l16 * 2];
    uint4 vb1 = hb4[(size_t)s1 * 32 + l16 * 2 + 1];
    float a0 = __expf(leaky(e0 + aldv));
    float a1 = __expf(leaky(e1 + aldv));
    dsum += a0 + a1;
    accum8(a0, va0, acc);
    accum8(a0, vb0, acc + 8);
    accum8(a1, va1, acc);
    accum8(a1, vb1, acc + 8);
  }
  for (; j < dg; j += 4) {
    int s0 = csr_src[rs + j];
    float e0 = als[s0 * 4 + head];
    uint4 va0 = hb4[(size_t)s0 * 32 + l16 * 2];
    uint4 vb0 = hb4[(size_t)s0 * 32 + l16 * 2 + 1];
    float a0 = __expf(leaky(e0 + aldv));
    dsum += a0;
    accum8(a0, va0, acc);
    accum8(a0, vb0, acc + 8);
  }
#pragma unroll
  for (int k = 0; k < 16; ++k) {
    acc[k] += __shfl_xor(acc[k], 16, 64);
    acc[k] += __shfl_xor(acc[k], 32, 64);
  }
  dsum += __shfl_xor(dsum, 16, 64);
  dsum += __shfl_xor(dsum, 32, 64);
  if (slot == 0) {  // channels [l16*16, l16*16+16), relu (both H=4 layers)
    const float inv = 1.f / (dsum + 1e-16f);
    const float* bz = bias + l16 * 16;
    uint4 o0, o1;
    float c0, c1;
    c0 = fmaxf(acc[0] * inv + bz[0], 0.f);   c1 = fmaxf(acc[1] * inv + bz[1], 0.f);
    o0.x = ((unsigned int)f2bf(c1) << 16) | f2bf(c0);
    c0 = fmaxf(acc[2] * inv + bz[2], 0.f);   c1 = fmaxf(acc[3] * inv + bz[3], 0.f);
    o0.y = ((unsigned int)f2bf(c1) << 16) | f2bf(c0);
    c0 = fmaxf(acc[4] * inv + bz[4], 0.f);   c1 = fmaxf(acc[5] * inv + bz[5], 0.f);
    o0.z = ((unsigned int)f2bf(c1) << 16) | f2bf(c0);
    c0 = fmaxf(acc[6] * inv + bz[6], 0.f);   c1 = fmaxf(acc[7] * inv + bz[7], 0.f);
    o0.w = ((unsigned int)f2bf(c1) << 16) | f2bf(c0);
    c0 = fmaxf(acc[8] * inv + bz[8], 0.f);   c1 = fmaxf(acc[9] * inv + bz[9], 0.f);
    o1.x = ((unsigned int)f2bf(c1) << 16) | f2bf(c0);
    c0 = fmaxf(acc[10] * inv + bz[10], 0.f); c1 = fmaxf(acc[11] * inv + bz[11], 0.f);
    o1.y = ((unsigned int)f2bf(c1) << 16) | f2bf(c0);
    c0 = fmaxf(acc[12] * inv + bz[12], 0.f); c1 = fmaxf(acc[13] * inv + bz[13], 0.f);
    o1.z = ((unsigned int)f2bf(c1) << 16) | f2bf(c0);
    c0 = fmaxf(acc[14] * inv + bz[14], 0.f); c1 = fmaxf(acc[15] * inv + bz[15], 0.f);
    o1.w = ((unsigned int)f2bf(c1) << 16) | f2bf(c0);
    out4[(size_t)dst * 32 + l16 * 2] = o0;
    out4[(size_t)dst * 32 + l16 * 2 + 1] = o1;
  }
}

// ====== gather-aggregate, inline alpha + den-sum, H=1: 8 slots x 8 lanes ====
__global__ __launch_bounds__(256) void aggr1c_k(const int* __restrict__ rowptr,
                                                const int* __restrict__ deg,
                                                const int* __restrict__ csr_src,
                                                const float* __restrict__ als,
                                                const float* __restrict__ ald,
                                                const float* __restrict__ selfex,
                                                const uint4* __restrict__ hb4,
                                                const float* __restrict__ bias,
                                                float* __restrict__ out) {
  const int dst = blockIdx.x * 4 + (threadIdx.x >> 6);
  const int lane = threadIdx.x & 63;
  const int slot = lane >> 3;
  const int c8 = lane & 7;
  const int rs = rowptr[dst];
  const int dg = deg[dst];
  const float aldv = ald[dst];

  float acc[8] = {};
  float dsum = 0.f;
  if (slot == 0) {
    float a = selfex[dst];
    dsum += a;
    uint4 v = hb4[(size_t)dst * 8 + c8];
    accum8(a, v, acc);
  }
  for (int j = slot; j < dg; j += 8) {
    int s = csr_src[rs + j];
    float e = als[s];
    uint4 v = hb4[(size_t)s * 8 + c8];
    float a = __expf(leaky(e + aldv));
    dsum += a;
    accum8(a, v, acc);
  }
#pragma unroll
  for (int k = 0; k < 8; ++k) {
    acc[k] += __shfl_xor(acc[k], 8, 64);
    acc[k] += __shfl_xor(acc[k], 16, 64);
    acc[k] += __shfl_xor(acc[k], 32, 64);
  }
  dsum += __shfl_xor(dsum, 8, 64);
  dsum += __shfl_xor(dsum, 16, 64);
  dsum += __shfl_xor(dsum, 32, 64);
  if (slot == 0) {  // no relu on layer 2; fp32 out
    const float inv = 1.f / (dsum + 1e-16f);
    const float4 bz0 = *(const float4*)(bias + c8 * 8);
    const float4 bz1 = *(const float4*)(bias + c8 * 8 + 4);
    float4 o0 = make_float4(acc[0] * inv + bz0.x, acc[1] * inv + bz0.y,
                            acc[2] * inv + bz0.z, acc[3] * inv + bz0.w);
    float4 o1 = make_float4(acc[4] * inv + bz1.x, acc[5] * inv + bz1.y,
                            acc[6] * inv + bz1.z, acc[7] * inv + bz1.w);
    *(float4*)(out + (size_t)dst * 64 + c8 * 8) = o0;
    *(float4*)(out + (size_t)dst * 64 + c8 * 8 + 4) = o1;
  }
}

// ---- fused prep: x->bf16 cast (blocks 0..12499) + 3 weight transposes ------
__global__ __launch_bounds__(256) void prep_k(const float2* __restrict__ x2,
                                              unsigned int* __restrict__ xb_u,
                                              const float* __restrict__ W0,
                                              unsigned short* __restrict__ W0t,
                                              const float* __restrict__ W1,
                                              unsigned short* __restrict__ W1t,
                                              const float* __restrict__ W2,
                                              unsigned short* __restrict__ W2t) {
  int bid = blockIdx.x;
  int tid = threadIdx.x;
  if (bid < 12500) {  // castx: NN*128/2 = 3.2M uints
    int i = bid * 256 + tid;
    float2 v = x2[i];
    xb_u[i] = ((unsigned int)f2bf(v.y) << 16) | f2bf(v.x);
    return;
  }
  int r = (bid - 12500) * 256 + tid;
  if (r < 32768) {            // W0t[256][128] <- W0[128][256]
    int n = r >> 7, k = r & 127;
    W0t[n * 128 + k] = f2bf(W0[k * 256 + n]);
  } else if (r < 98304) {     // W1t[256][256] <- W1[256][256]
    int rr = r - 32768;
    int n = rr >> 8, k = rr & 255;
    W1t[n * 256 + k] = f2bf(W1[k * 256 + n]);
  } else {                    // W2t[64][256] <- W2[256][64]
    int rr = r - 98304;
    int n = rr >> 8, k = rr & 255;
    W2t[n * 256 + k] = f2bf(W2[k * 64 + n]);
  }
}

// ---- colsum + fused head: last block computes the final [1,64] output ------
__global__ __launch_bounds__(256) void colsum_head_k(const float* __restrict__ h2,
                                                     float* __restrict__ g,
                                                     unsigned int* __restrict__ cnt,
                                                     const float* __restrict__ hw,
                                                     const float* __restrict__ hb,
                                                     float* __restrict__ out) {
  __shared__ float s[256];
  __shared__ float sg[64];
  __shared__ unsigned int sdone;
  int tid = threadIdx.x;
  int c = tid & 63, rg = tid >> 6;
  float acc = 0.f;
  for (int n = blockIdx.x * 4 + rg; n < NN; n += gridDim.x * 4)
    acc += h2[n * 64 + c];
  s[tid] = acc;
  __syncthreads();
  if (tid < 64) atomicAdd(&g[c], s[c] + s[64 + c] + s[128 + c] + s[192 + c]);
  __threadfence();
  __syncthreads();
  if (tid == 0) sdone = atomicAdd(cnt, 1);
  __syncthreads();
  if (sdone != gridDim.x - 1) return;
  // last block: all other blocks' g-atomics are complete (fence+counter order)
  if (tid < 64) sg[tid] = atomicAdd(&g[tid], 0.f);  // coherent read
  __syncthreads();
  if (tid < 64) {
    const float invN = 1.0f / (float)NN;
    float a2 = hb[tid];
#pragma unroll 8
    for (int cc = 0; cc < 64; ++cc) a2 += sg[cc] * invN * hw[cc * 64 + tid];
    out[tid] = a2;
  }
}

extern "C" void kernel_launch(void* const* d_in, const int* in_sizes, int n_in,
                              void* d_out, int out_size, void* d_ws, size_t ws_size,
                              hipStream_t stream) {
  const float* x   = (const float*)d_in[0];
  const int*   ei  = (const int*)d_in[1];
  const float* W0  = (const float*)d_in[2];
  const float* a0s = (const float*)d_in[3];
  const float* a0d = (const float*)d_in[4];
  const float* b0  = (const float*)d_in[5];
  const float* W1  = (const float*)d_in[6];
  const float* a1s = (const float*)d_in[7];
  const float* a1d = (const float*)d_in[8];
  const float* b1  = (const float*)d_in[9];
  const float* W2  = (const float*)d_in[10];
  const float* a2s = (const float*)d_in[11];
  const float* a2d = (const float*)d_in[12];
  const float* b2  = (const float*)d_in[13];
  const float* hw  = (const float*)d_in[14];
  const float* hb  = (const float*)d_in[15];
  float* out = (float*)d_out;

  char* w = (char*)d_ws;
  unsigned short* xb   = (unsigned short*)w; w += (size_t)NN * 128 * 2;
  unsigned short* bufG = (unsigned short*)w; w += (size_t)NN * 256 * 2;
  unsigned short* bufA = (unsigned short*)w; w += (size_t)NN * 256 * 2;
  float* bufF = (float*)w;                   w += (size_t)NN * 64 * 4;
  unsigned short* W0t = (unsigned short*)w;  w += 256 * 128 * 2;
  unsigned short* W1t = (unsigned short*)w;  w += 256 * 256 * 2;
  unsigned short* W2t = (unsigned short*)w;  w += 64 * 256 * 2;
  float* als  = (float*)w;    w += (size_t)NN * 4 * 4;
  float* ald  = (float*)w;    w += (size_t)NN * 4 * 4;
  float* sfx  = (float*)w;    w += (size_t)NN * 4 * 4;
  int* deg     = (int*)w;     w += (size_t)NN * 4;
  int* rowptr  = (int*)w;     w += (size_t)NN * 4;
  int* cursor  = (int*)w;     w += (size_t)NN * 4;
  int* incl    = (int*)w;     w += (size_t)NN * 4;
  int* partial = (int*)w;     w += 256 * 4;
  int* csr_src = (int*)w;     w += (size_t)EE * 4;
  float* g    = (float*)w;    w += 256;           // g[0..63] sums; cnt at g+64

  // ---- CSR build (shared by all 3 layers) ----
  hipMemsetAsync(deg, 0, (size_t)NN * 4, stream);
  hist_k<<<(EE + 255) / 256, 256, 0, stream>>>(ei, deg);
  scan1_k<<<NB, 256, 0, stream>>>(deg, incl, partial);
  scan2_k<<<1, 256, 0, stream>>>(partial);
  scan3_k<<<NB, 256, 0, stream>>>(deg, incl, partial, rowptr, cursor);
  scatter_k<<<(EE + 255) / 256, 256, 0, stream>>>(ei, cursor, csr_src);

  // ---- fused prep: cast + 3 transposes ----
  prep_k<<<12500 + 448, 256, 0, stream>>>((const float2*)x, (unsigned int*)xb,
                                          W0, W0t, W1, W1t, W2, W2t);

  const int GX = (NN + 127) / 128;
  const int GA = NN / 4;   // 12500 exact

  auto layer4 = [&](const unsigned short* in, int K, const unsigned short* Wt,
                    const float* a_s, const float* a_d, const float* bias,
                    unsigned short* hbuf, unsigned short* obuf) {
    gemm_bf16_k<<<dim3(GX, 4), 256, 0, stream>>>(in, Wt, hbuf, K, 256,
                                                 a_s, a_d, als, ald, sfx);
    aggr4c_k<<<GA, 256, 0, stream>>>(rowptr, deg, csr_src, als, ald, sfx,
                                     (const uint4*)hbuf, bias, (uint4*)obuf);
  };

  // layers 0 and 1 (H=4)
  layer4(xb, 128, W0t, a0s, a0d, b0, bufG, bufA);
  layer4(bufA, 256, W1t, a1s, a1d, b1, bufG, bufA);

  // layer 2 (H=1)
  gemm_bf16_k<<<dim3(GX, 1), 256, 0, stream>>>(bufA, W2t, bufG, 256, 64,
                                               a2s, a2d, als, ald, sfx);
  aggr1c_k<<<GA, 256, 0, stream>>>(rowptr, deg, csr_src, als, ald, sfx,
                                   (const uint4*)bufG, b2, bufF);

  // ---- mean + head (fused; g[0..63] sums, counter at g+64) ----
  hipMemsetAsync(g, 0, 68 * 4, stream);
  colsum_head_k<<<256, 256, 0, stream>>>(bufF, g, (unsigned int*)(g + 64), hw, hb, out);
}

// Round 13
// 440.090 us; speedup vs baseline: 1.0646x; 1.0019x over previous
//
#include <hip/hip_runtime.h>
#include <hip/hip_bf16.h>
#include <cstddef>

#define NN 50000
#define EE 800000
#define NB ((NN + 255) / 256)

typedef __attribute__((ext_vector_type(8))) short short8;
typedef __attribute__((ext_vector_type(4))) float f32x4;

__device__ __forceinline__ float leaky(float x) { return x >= 0.f ? x : 0.2f * x; }
__device__ __forceinline__ float bf2f(unsigned short u) {
  return __uint_as_float(((unsigned int)u) << 16);
}
__device__ __forceinline__ float bflo(unsigned int v) { return __uint_as_float(v << 16); }
__device__ __forceinline__ float bfhi(unsigned int v) { return __uint_as_float(v & 0xFFFF0000u); }
__device__ __forceinline__ unsigned short f2bf(float f) {
  __hip_bfloat16 b = __float2bfloat16(f);
  return __builtin_bit_cast(unsigned short, b);
}
__device__ __forceinline__ float selh(float4 v, int h) {
  float a = (h & 1) ? v.y : v.x;
  float b = (h & 1) ? v.w : v.z;
  return (h & 2) ? b : a;
}
__device__ __forceinline__ void accum8(float a, uint4 v, float* acc) {
  acc[0] += a * bflo(v.x); acc[1] += a * bfhi(v.x);
  acc[2] += a * bflo(v.y); acc[3] += a * bfhi(v.y);
  acc[4] += a * bflo(v.z); acc[5] += a * bfhi(v.z);
  acc[6] += a * bflo(v.w); acc[7] += a * bfhi(v.w);
}

// ==== bf16 MFMA GEMM + fused attention-logit epilogue =======================
__global__ __launch_bounds__(256) void gemm_bf16_k(const unsigned short* __restrict__ A,
                                                   const unsigned short* __restrict__ Bt,
                                                   unsigned short* __restrict__ Cb,
                                                   int K, int Nfull,
                                                   const float* __restrict__ a_s,
                                                   const float* __restrict__ a_d,
                                                   float* __restrict__ als,
                                                   float* __restrict__ ald,
                                                   float* __restrict__ selfex) {
  __shared__ __align__(16) unsigned short As[128 * 40];
  __shared__ __align__(16) unsigned short Bs[64 * 40];
  const int tid = threadIdx.x;
  const int lane = tid & 63;
  const int w = tid >> 6;
  const int bm = blockIdx.x * 128;
  const int bn = blockIdx.y * 64;
  const int quad = lane >> 4;
  const int l16 = lane & 15;
  f32x4 acc[2][4] = {};
  for (int kc = 0; kc < K; kc += 32) {
    {
      int row = tid >> 2, seg = tid & 3;
      int sr = bm + row; if (sr >= NN) sr = NN - 1;
      *(uint4*)&As[row * 40 + seg * 8] = *(const uint4*)(A + (size_t)sr * K + kc + seg * 8);
      row = (tid + 256) >> 2; seg = (tid + 256) & 3;
      sr = bm + row; if (sr >= NN) sr = NN - 1;
      *(uint4*)&As[row * 40 + seg * 8] = *(const uint4*)(A + (size_t)sr * K + kc + seg * 8);
      int n = tid >> 2; seg = tid & 3;
      *(uint4*)&Bs[n * 40 + seg * 8] = *(const uint4*)(Bt + (size_t)(bn + n) * K + kc + seg * 8);
    }
    __syncthreads();
    short8 afr0 = *(const short8*)&As[(w * 32 + l16) * 40 + quad * 8];
    short8 afr1 = *(const short8*)&As[(w * 32 + 16 + l16) * 40 + quad * 8];
#pragma unroll
    for (int nt = 0; nt < 4; ++nt) {
      short8 bfr = *(const short8*)&Bs[(nt * 16 + l16) * 40 + quad * 8];
      acc[0][nt] = __builtin_amdgcn_mfma_f32_16x16x32_bf16(afr0, bfr, acc[0][nt], 0, 0, 0);
      acc[1][nt] = __builtin_amdgcn_mfma_f32_16x16x32_bf16(afr1, bfr, acc[1][nt], 0, 0, 0);
    }
    __syncthreads();
  }
  const int head = bn >> 6;
  const int Hmul = Nfull >> 6;
  float vs[2][4] = {};
  float vd[2][4] = {};
#pragma unroll
  for (int nt = 0; nt < 4; ++nt) {
    const float asv = a_s[head * 64 + nt * 16 + l16];
    const float adv = a_d[head * 64 + nt * 16 + l16];
#pragma unroll
    for (int mt = 0; mt < 2; ++mt)
#pragma unroll
      for (int reg = 0; reg < 4; ++reg) {
        unsigned short c = f2bf(acc[mt][nt][reg]);
        int r = bm + w * 32 + mt * 16 + quad * 4 + reg;
        if (r < NN) Cb[(size_t)r * Nfull + bn + nt * 16 + l16] = c;
        float hv = bf2f(c);
        vs[mt][reg] += hv * asv;
        vd[mt][reg] += hv * adv;
      }
  }
#pragma unroll
  for (int off = 1; off < 16; off <<= 1) {
#pragma unroll
    for (int mt = 0; mt < 2; ++mt)
#pragma unroll
      for (int reg = 0; reg < 4; ++reg) {
        vs[mt][reg] += __shfl_xor(vs[mt][reg], off, 64);
        vd[mt][reg] += __shfl_xor(vd[mt][reg], off, 64);
      }
  }
  if (l16 == 0) {
#pragma unroll
    for (int mt = 0; mt < 2; ++mt)
#pragma unroll
      for (int reg = 0; reg < 4; ++reg) {
        int r = bm + w * 32 + mt * 16 + quad * 4 + reg;
        if (r < NN) {
          als[(size_t)r * Hmul + head] = vs[mt][reg];
          ald[(size_t)r * Hmul + head] = vd[mt][reg];
          selfex[(size_t)r * Hmul + head] = __expf(leaky(vs[mt][reg] + vd[mt][reg]));
        }
      }
  }
}

// ================= CSR build (topology is layer-invariant) ==================
__global__ __launch_bounds__(256) void hist_k(const int* __restrict__ ei, int* deg) {
  int i = blockIdx.x * 256 + threadIdx.x;
  if (i < EE) atomicAdd(&deg[ei[EE + i]], 1);
}

__global__ __launch_bounds__(256) void scan1_k(const int* __restrict__ deg,
                                               int* __restrict__ incl,
                                               int* __restrict__ partial) {
  __shared__ int s[256];
  int t = threadIdx.x;
  int i = blockIdx.x * 256 + t;
  int v = (i < NN) ? deg[i] : 0;
  s[t] = v;
  __syncthreads();
  for (int off = 1; off < 256; off <<= 1) {
    int u = (t >= off) ? s[t - off] : 0;
    __syncthreads();
    s[t] += u;
    __syncthreads();
  }
  if (i < NN) incl[i] = s[t];
  if (t == 255) partial[blockIdx.x] = s[255];
}

__global__ void scan2_k(int* __restrict__ partial) {
  __shared__ int s[256];
  int t = threadIdx.x;
  int v = (t < NB) ? partial[t] : 0;
  s[t] = v;
  __syncthreads();
  for (int off = 1; off < 256; off <<= 1) {
    int u = (t >= off) ? s[t - off] : 0;
    __syncthreads();
    s[t] += u;
    __syncthreads();
  }
  if (t < NB) partial[t] = s[t] - v;  // exclusive
}

__global__ __launch_bounds__(256) void scan3_k(const int* __restrict__ deg,
                                               const int* __restrict__ incl,
                                               const int* __restrict__ partial,
                                               int* __restrict__ rowptr,
                                               int* __restrict__ cursor) {
  int i = blockIdx.x * 256 + threadIdx.x;
  if (i >= NN) return;
  int r = partial[blockIdx.x] + incl[i] - deg[i];
  rowptr[i] = r;
  cursor[i] = r;
}

__global__ __launch_bounds__(256) void scatter_k(const int* __restrict__ ei,
                                                 int* __restrict__ cursor,
                                                 int* __restrict__ csr_src) {
  int i = blockIdx.x * 256 + threadIdx.x;
  if (i >= EE) return;
  int d = ei[EE + i];
  int p = atomicAdd(&cursor[d], 1);
  csr_src[p] = ei[i];
}

// ====== gather-aggregate H=4, LDS-staged index/alpha ========================
// Per 64-edge chunk: all 64 lanes cooperatively load csr_src (coalesced) and
// compute all 4 heads' alpha ONCE per edge into per-wave LDS. The gather loop
// then has only ONE global-latency level (the h-row load) in its dependent
// chain — indices/alphas come from LDS. Chunk count is block-uniform (max of
// the 4 dsts' degrees) so __syncthreads counts match. Zero atomics.
__global__ __launch_bounds__(256) void aggr4c_k(const int* __restrict__ rowptr,
                                                const int* __restrict__ deg,
                                                const int* __restrict__ csr_src,
                                                const float* __restrict__ als,
                                                const float* __restrict__ ald,
                                                const float* __restrict__ selfex,
                                                const uint4* __restrict__ hb4,
                                                const float* __restrict__ bias,
                                                uint4* __restrict__ out4) {
  __shared__ int sidx[4][64];
  __shared__ float4 salf[4][64];
  const int wv = threadIdx.x >> 6;
  const int dst0 = blockIdx.x * 4;
  const int dst = dst0 + wv;
  const int lane = threadIdx.x & 63;
  const int slot = lane >> 4;
  const int l16 = lane & 15;
  const int head = l16 >> 2;
  const int rs = rowptr[dst];
  const int dg = deg[dst];
  const int maxdg = max(max(deg[dst0], deg[dst0 + 1]), max(deg[dst0 + 2], deg[dst0 + 3]));
  const float4 ald4 = *(const float4*)(ald + (size_t)dst * 4);

  float acc[16] = {};
  float dsum = 0.f;
  if (slot == 0) {  // self-loop (unnormalized)
    float a = selfex[dst * 4 + head];
    dsum += a;
    uint4 v0 = hb4[(size_t)dst * 32 + l16 * 2];
    uint4 v1 = hb4[(size_t)dst * 32 + l16 * 2 + 1];
    accum8(a, v0, acc);
    accum8(a, v1, acc + 8);
  }

  for (int chunk = 0; chunk < maxdg; chunk += 64) {
    int n = dg - chunk;  // may be <= 0 for this wave
    __syncthreads();     // protect LDS regions before overwrite (uniform count)
    if (lane < n) {
      int s = csr_src[rs + chunk + lane];
      float4 as4 = *(const float4*)(als + (size_t)s * 4);
      float4 e;
      e.x = __expf(leaky(as4.x + ald4.x));
      e.y = __expf(leaky(as4.y + ald4.y));
      e.z = __expf(leaky(as4.z + ald4.z));
      e.w = __expf(leaky(as4.w + ald4.w));
      sidx[wv][lane] = s;
      salf[wv][lane] = e;
    }
    __syncthreads();
    int m = n < 64 ? n : 64;
    int j = slot;
    for (; j + 4 < m; j += 8) {  // 2-edge unroll; idx/alpha from LDS
      int s0 = sidx[wv][j];
      int s1 = sidx[wv][j + 4];
      float a0 = selh(salf[wv][j], head);
      float a1 = selh(salf[wv][j + 4], head);
      uint4 va0 = hb4[(size_t)s0 * 32 + l16 * 2];
      uint4 vb0 = hb4[(size_t)s0 * 32 + l16 * 2 + 1];
      uint4 va1 = hb4[(size_t)s1 * 32 + l16 * 2];
      uint4 vb1 = hb4[(size_t)s1 * 32 + l16 * 2 + 1];
      dsum += a0 + a1;
      accum8(a0, va0, acc);
      accum8(a0, vb0, acc + 8);
      accum8(a1, va1, acc);
      accum8(a1, vb1, acc + 8);
    }
    for (; j < m; j += 4) {
      int s0 = sidx[wv][j];
      float a0 = selh(salf[wv][j], head);
      uint4 va0 = hb4[(size_t)s0 * 32 + l16 * 2];
      uint4 vb0 = hb4[(size_t)s0 * 32 + l16 * 2 + 1];
      dsum += a0;
      accum8(a0, va0, acc);
      accum8(a0, vb0, acc + 8);
    }
  }
#pragma unroll
  for (int k = 0; k < 16; ++k) {
    acc[k] += __shfl_xor(acc[k], 16, 64);
    acc[k] += __shfl_xor(acc[k], 32, 64);
  }
  dsum += __shfl_xor(dsum, 16, 64);
  dsum += __shfl_xor(dsum, 32, 64);
  if (slot == 0) {  // channels [l16*16, l16*16+16), relu (both H=4 layers)
    const float inv = 1.f / (dsum + 1e-16f);
    const float* bz = bias + l16 * 16;
    uint4 o0, o1;
    float c0, c1;
    c0 = fmaxf(acc[0] * inv + bz[0], 0.f);   c1 = fmaxf(acc[1] * inv + bz[1], 0.f);
    o0.x = ((unsigned int)f2bf(c1) << 16) | f2bf(c0);
    c0 = fmaxf(acc[2] * inv + bz[2], 0.f);   c1 = fmaxf(acc[3] * inv + bz[3], 0.f);
    o0.y = ((unsigned int)f2bf(c1) << 16) | f2bf(c0);
    c0 = fmaxf(acc[4] * inv + bz[4], 0.f);   c1 = fmaxf(acc[5] * inv + bz[5], 0.f);
    o0.z = ((unsigned int)f2bf(c1) << 16) | f2bf(c0);
    c0 = fmaxf(acc[6] * inv + bz[6], 0.f);   c1 = fmaxf(acc[7] * inv + bz[7], 0.f);
    o0.w = ((unsigned int)f2bf(c1) << 16) | f2bf(c0);
    c0 = fmaxf(acc[8] * inv + bz[8], 0.f);   c1 = fmaxf(acc[9] * inv + bz[9], 0.f);
    o1.x = ((unsigned int)f2bf(c1) << 16) | f2bf(c0);
    c0 = fmaxf(acc[10] * inv + bz[10], 0.f); c1 = fmaxf(acc[11] * inv + bz[11], 0.f);
    o1.y = ((unsigned int)f2bf(c1) << 16) | f2bf(c0);
    c0 = fmaxf(acc[12] * inv + bz[12], 0.f); c1 = fmaxf(acc[13] * inv + bz[13], 0.f);
    o1.z = ((unsigned int)f2bf(c1) << 16) | f2bf(c0);
    c0 = fmaxf(acc[14] * inv + bz[14], 0.f); c1 = fmaxf(acc[15] * inv + bz[15], 0.f);
    o1.w = ((unsigned int)f2bf(c1) << 16) | f2bf(c0);
    out4[(size_t)dst * 32 + l16 * 2] = o0;
    out4[(size_t)dst * 32 + l16 * 2 + 1] = o1;
  }
}

// ====== gather-aggregate H=1, LDS-staged index/alpha: 8 slots x 8 lanes =====
__global__ __launch_bounds__(256) void aggr1c_k(const int* __restrict__ rowptr,
                                                const int* __restrict__ deg,
                                                const int* __restrict__ csr_src,
                                                const float* __restrict__ als,
                                                const float* __restrict__ ald,
                                                const float* __restrict__ selfex,
                                                const uint4* __restrict__ hb4,
                                                const float* __restrict__ bias,
                                                float* __restrict__ out) {
  __shared__ int sidx[4][64];
  __shared__ float salf[4][64];
  const int wv = threadIdx.x >> 6;
  const int dst0 = blockIdx.x * 4;
  const int dst = dst0 + wv;
  const int lane = threadIdx.x & 63;
  const int slot = lane >> 3;
  const int c8 = lane & 7;
  const int rs = rowptr[dst];
  const int dg = deg[dst];
  const int maxdg = max(max(deg[dst0], deg[dst0 + 1]), max(deg[dst0 + 2], deg[dst0 + 3]));
  const float aldv = ald[dst];

  float acc[8] = {};
  float dsum = 0.f;
  if (slot == 0) {
    float a = selfex[dst];
    dsum += a;
    uint4 v = hb4[(size_t)dst * 8 + c8];
    accum8(a, v, acc);
  }
  for (int chunk = 0; chunk < maxdg; chunk += 64) {
    int n = dg - chunk;
    __syncthreads();
    if (lane < n) {
      int s = csr_src[rs + chunk + lane];
      sidx[wv][lane] = s;
      salf[wv][lane] = __expf(leaky(als[s] + aldv));
    }
    __syncthreads();
    int m = n < 64 ? n : 64;
    int j = slot;
    for (; j + 8 < m; j += 16) {
      int s0 = sidx[wv][j];
      int s1 = sidx[wv][j + 8];
      float a0 = salf[wv][j];
      float a1 = salf[wv][j + 8];
      uint4 v0 = hb4[(size_t)s0 * 8 + c8];
      uint4 v1 = hb4[(size_t)s1 * 8 + c8];
      dsum += a0 + a1;
      accum8(a0, v0, acc);
      accum8(a1, v1, acc);
    }
    for (; j < m; j += 8) {
      int s = sidx[wv][j];
      float a = salf[wv][j];
      uint4 v = hb4[(size_t)s * 8 + c8];
      dsum += a;
      accum8(a, v, acc);
    }
  }
#pragma unroll
  for (int k = 0; k < 8; ++k) {
    acc[k] += __shfl_xor(acc[k], 8, 64);
    acc[k] += __shfl_xor(acc[k], 16, 64);
    acc[k] += __shfl_xor(acc[k], 32, 64);
  }
  dsum += __shfl_xor(dsum, 8, 64);
  dsum += __shfl_xor(dsum, 16, 64);
  dsum += __shfl_xor(dsum, 32, 64);
  if (slot == 0) {  // no relu on layer 2; fp32 out
    const float inv = 1.f / (dsum + 1e-16f);
    const float4 bz0 = *(const float4*)(bias + c8 * 8);
    const float4 bz1 = *(const float4*)(bias + c8 * 8 + 4);
    float4 o0 = make_float4(acc[0] * inv + bz0.x, acc[1] * inv + bz0.y,
                            acc[2] * inv + bz0.z, acc[3] * inv + bz0.w);
    float4 o1 = make_float4(acc[4] * inv + bz1.x, acc[5] * inv + bz1.y,
                            acc[6] * inv + bz1.z, acc[7] * inv + bz1.w);
    *(float4*)(out + (size_t)dst * 64 + c8 * 8) = o0;
    *(float4*)(out + (size_t)dst * 64 + c8 * 8 + 4) = o1;
  }
}

// ---- fused prep: x->bf16 cast (blocks 0..12499) + 3 weight transposes ------
__global__ __launch_bounds__(256) void prep_k(const float2* __restrict__ x2,
                                              unsigned int* __restrict__ xb_u,
                                              const float* __restrict__ W0,
                                              unsigned short* __restrict__ W0t,
                                              const float* __restrict__ W1,
                                              unsigned short* __restrict__ W1t,
                                              const float* __restrict__ W2,
                                              unsigned short* __restrict__ W2t) {
  int bid = blockIdx.x;
  int tid = threadIdx.x;
  if (bid < 12500) {  // castx: NN*128/2 = 3.2M uints
    int i = bid * 256 + tid;
    float2 v = x2[i];
    xb_u[i] = ((unsigned int)f2bf(v.y) << 16) | f2bf(v.x);
    return;
  }
  int r = (bid - 12500) * 256 + tid;
  if (r < 32768) {            // W0t[256][128] <- W0[128][256]
    int n = r >> 7, k = r & 127;
    W0t[n * 128 + k] = f2bf(W0[k * 256 + n]);
  } else if (r < 98304) {     // W1t[256][256] <- W1[256][256]
    int rr = r - 32768;
    int n = rr >> 8, k = rr & 255;
    W1t[n * 256 + k] = f2bf(W1[k * 256 + n]);
  } else {                    // W2t[64][256] <- W2[256][64]
    int rr = r - 98304;
    int n = rr >> 8, k = rr & 255;
    W2t[n * 256 + k] = f2bf(W2[k * 64 + n]);
  }
}

// ---- colsum + fused head: last block computes the final [1,64] output ------
__global__ __launch_bounds__(256) void colsum_head_k(const float* __restrict__ h2,
                                                     float* __restrict__ g,
                                                     unsigned int* __restrict__ cnt,
                                                     const float* __restrict__ hw,
                                                     const float* __restrict__ hb,
                                                     float* __restrict__ out) {
  __shared__ float s[256];
  __shared__ float sg[64];
  __shared__ unsigned int sdone;
  int tid = threadIdx.x;
  int c = tid & 63, rg = tid >> 6;
  float acc = 0.f;
  for (int n = blockIdx.x * 4 + rg; n < NN; n += gridDim.x * 4)
    acc += h2[n * 64 + c];
  s[tid] = acc;
  __syncthreads();
  if (tid < 64) atomicAdd(&g[c], s[c] + s[64 + c] + s[128 + c] + s[192 + c]);
  __threadfence();
  __syncthreads();
  if (tid == 0) sdone = atomicAdd(cnt, 1);
  __syncthreads();
  if (sdone != gridDim.x - 1) return;
  // last block: all other blocks' g-atomics are complete (fence+counter order)
  if (tid < 64) sg[tid] = atomicAdd(&g[tid], 0.f);  // coherent read
  __syncthreads();
  if (tid < 64) {
    const float invN = 1.0f / (float)NN;
    float a2 = hb[tid];
#pragma unroll 8
    for (int cc = 0; cc < 64; ++cc) a2 += sg[cc] * invN * hw[cc * 64 + tid];
    out[tid] = a2;
  }
}

extern "C" void kernel_launch(void* const* d_in, const int* in_sizes, int n_in,
                              void* d_out, int out_size, void* d_ws, size_t ws_size,
                              hipStream_t stream) {
  const float* x   = (const float*)d_in[0];
  const int*   ei  = (const int*)d_in[1];
  const float* W0  = (const float*)d_in[2];
  const float* a0s = (const float*)d_in[3];
  const float* a0d = (const float*)d_in[4];
  const float* b0  = (const float*)d_in[5];
  const float* W1  = (const float*)d_in[6];
  const float* a1s = (const float*)d_in[7];
  const float* a1d = (const float*)d_in[8];
  const float* b1  = (const float*)d_in[9];
  const float* W2  = (const float*)d_in[10];
  const float* a2s = (const float*)d_in[11];
  const float* a2d = (const float*)d_in[12];
  const float* b2  = (const float*)d_in[13];
  const float* hw  = (const float*)d_in[14];
  const float* hb  = (const float*)d_in[15];
  float* out = (float*)d_out;

  char* w = (char*)d_ws;
  unsigned short* xb   = (unsigned short*)w; w += (size_t)NN * 128 * 2;
  unsigned short* bufG = (unsigned short*)w; w += (size_t)NN * 256 * 2;
  unsigned short* bufA = (unsigned short*)w; w += (size_t)NN * 256 * 2;
  float* bufF = (float*)w;                   w += (size_t)NN * 64 * 4;
  unsigned short* W0t = (unsigned short*)w;  w += 256 * 128 * 2;
  unsigned short* W1t = (unsigned short*)w;  w += 256 * 256 * 2;
  unsigned short* W2t = (unsigned short*)w;  w += 64 * 256 * 2;
  float* als  = (float*)w;    w += (size_t)NN * 4 * 4;
  float* ald  = (float*)w;    w += (size_t)NN * 4 * 4;
  float* sfx  = (float*)w;    w += (size_t)NN * 4 * 4;
  int* deg     = (int*)w;     w += (size_t)NN * 4;
  int* rowptr  = (int*)w;     w += (size_t)NN * 4;
  int* cursor  = (int*)w;     w += (size_t)NN * 4;
  int* incl    = (int*)w;     w += (size_t)NN * 4;
  int* partial = (int*)w;     w += 256 * 4;
  int* csr_src = (int*)w;     w += (size_t)EE * 4;
  float* g    = (float*)w;    w += 256;           // g[0..63] sums; cnt at g+64

  // ---- CSR build (shared by all 3 layers) ----
  hipMemsetAsync(deg, 0, (size_t)NN * 4, stream);
  hist_k<<<(EE + 255) / 256, 256, 0, stream>>>(ei, deg);
  scan1_k<<<NB, 256, 0, stream>>>(deg, incl, partial);
  scan2_k<<<1, 256, 0, stream>>>(partial);
  scan3_k<<<NB, 256, 0, stream>>>(deg, incl, partial, rowptr, cursor);
  scatter_k<<<(EE + 255) / 256, 256, 0, stream>>>(ei, cursor, csr_src);

  // ---- fused prep: cast + 3 transposes ----
  prep_k<<<12500 + 448, 256, 0, stream>>>((const float2*)x, (unsigned int*)xb,
                                          W0, W0t, W1, W1t, W2, W2t);

  const int GX = (NN + 127) / 128;
  const int GA = NN / 4;   // 12500 exact

  auto layer4 = [&](const unsigned short* in, int K, const unsigned short* Wt,
                    const float* a_s, const float* a_d, const float* bias,
                    unsigned short* hbuf, unsigned short* obuf) {
    gemm_bf16_k<<<dim3(GX, 4), 256, 0, stream>>>(in, Wt, hbuf, K, 256,
                                                 a_s, a_d, als, ald, sfx);
    aggr4c_k<<<GA, 256, 0, stream>>>(rowptr, deg, csr_src, als, ald, sfx,
                                     (const uint4*)hbuf, bias, (uint4*)obuf);
  };

  // layers 0 and 1 (H=4)
  layer4(xb, 128, W0t, a0s, a0d, b0, bufG, bufA);
  layer4(bufA, 256, W1t, a1s, a1d, b1, bufG, bufA);

  // layer 2 (H=1)
  gemm_bf16_k<<<dim3(GX, 1), 256, 0, stream>>>(bufA, W2t, bufG, 256, 64,
                                               a2s, a2d, als, ald, sfx);
  aggr1c_k<<<GA, 256, 0, stream>>>(rowptr, deg, csr_src, als, ald, sfx,
                                   (const uint4*)bufG, b2, bufF);

  // ---- mean + head (fused; g[0..63] sums, counter at g+64) ----
  hipMemsetAsync(g, 0, 68 * 4, stream);
  colsum_head_k<<<256, 256, 0, stream>>>(bufF, g, (unsigned int*)(g + 64), hw, hb, out);
}

// Round 14
// 437.510 us; speedup vs baseline: 1.0709x; 1.0059x over previous
//
#include <hip/hip_runtime.h>
#include <hip/hip_bf16.h>
#include <cstddef>

#define NN 50000
#define EE 800000
#define NB ((NN + 255) / 256)

typedef __attribute__((ext_vector_type(8))) short short8;
typedef __attribute__((ext_vector_type(4))) float f32x4;

#define GLB __attribute__((address_space(1)))
#define LDS __attribute__((address_space(3)))

__device__ __forceinline__ float leaky(float x) { return x >= 0.f ? x : 0.2f * x; }
__device__ __forceinline__ float bf2f(unsigned short u) {
  return __uint_as_float(((unsigned int)u) << 16);
}
__device__ __forceinline__ float bflo(unsigned int v) { return __uint_as_float(v << 16); }
__device__ __forceinline__ float bfhi(unsigned int v) { return __uint_as_float(v & 0xFFFF0000u); }
__device__ __forceinline__ unsigned short f2bf(float f) {
  __hip_bfloat16 b = __float2bfloat16(f);
  return __builtin_bit_cast(unsigned short, b);
}
__device__ __forceinline__ float selh(float4 v, int h) {
  float a = (h & 1) ? v.y : v.x;
  float b = (h & 1) ? v.w : v.z;
  return (h & 2) ? b : a;
}
__device__ __forceinline__ void accum8(float a, uint4 v, float* acc) {
  acc[0] += a * bflo(v.x); acc[1] += a * bfhi(v.x);
  acc[2] += a * bflo(v.y); acc[3] += a * bfhi(v.y);
  acc[4] += a * bflo(v.z); acc[5] += a * bfhi(v.z);
  acc[6] += a * bflo(v.w); acc[7] += a * bfhi(v.w);
}

// ==== bf16 MFMA GEMM + fused attention-logit epilogue =======================
// Staging via global_load_lds(16B): contiguous LDS tiles (no pad — required
// by the fixed lane->LDS mapping), with k-segment XOR swizzle seg^((row>>2)&3)
// applied at the GLOBAL fetch address so ds_read_b128 fragment reads alias at
// most 2-way (free). Removes the A/B VGPR round-trip of the old staging.
__global__ __launch_bounds__(256) void gemm_bf16_k(const unsigned short* __restrict__ A,
                                                   const unsigned short* __restrict__ Bt,
                                                   unsigned short* __restrict__ Cb,
                                                   int K, int Nfull,
                                                   const float* __restrict__ a_s,
                                                   const float* __restrict__ a_d,
                                                   float* __restrict__ als,
                                                   float* __restrict__ ald,
                                                   float* __restrict__ selfex) {
  __shared__ __align__(16) unsigned short As[128 * 32];  // 8 KB
  __shared__ __align__(16) unsigned short Bs[64 * 32];   // 4 KB
  const int tid = threadIdx.x;
  const int lane = tid & 63;
  const int w = tid >> 6;
  const int bm = blockIdx.x * 128;
  const int bn = blockIdx.y * 64;
  const int quad = lane >> 4;
  const int l16 = lane & 15;
  const int lrow = lane >> 2;   // 0..15 within a staging call
  const int lseg = lane & 3;
  f32x4 acc[2][4] = {};
  for (int kc = 0; kc < K; kc += 32) {
    // ---- A tile: 2 calls/wave, 16 rows each (row = 64B = 4 lanes x 16B) ----
#pragma unroll
    for (int c = 0; c < 2; ++c) {
      int row = w * 32 + c * 16 + lrow;
      int g = lseg ^ ((row >> 2) & 3);
      int sr = bm + row; if (sr >= NN) sr = NN - 1;
      const unsigned short* gp = A + (size_t)sr * K + kc + g * 8;
      __builtin_amdgcn_global_load_lds((const GLB void*)gp,
                                       (LDS void*)&As[(w * 32 + c * 16) * 32], 16, 0, 0);
    }
    // ---- B tile: 1 call/wave, 16 rows ----
    {
      int row = w * 16 + lrow;
      int g = lseg ^ ((row >> 2) & 3);
      const unsigned short* gp = Bt + (size_t)(bn + row) * K + kc + g * 8;
      __builtin_amdgcn_global_load_lds((const GLB void*)gp,
                                       (LDS void*)&Bs[(w * 16) * 32], 16, 0, 0);
    }
    __syncthreads();
    const int ra0 = w * 32 + l16;
    const int ra1 = ra0 + 16;  // (ra1>>2)&3 == (ra0>>2)&3 + 4 -> &3 unchanged
    short8 afr0 = *(const short8*)&As[ra0 * 32 + ((quad ^ ((ra0 >> 2) & 3)) << 3)];
    short8 afr1 = *(const short8*)&As[ra1 * 32 + ((quad ^ ((ra1 >> 2) & 3)) << 3)];
#pragma unroll
    for (int nt = 0; nt < 4; ++nt) {
      int rb = nt * 16 + l16;
      short8 bfr = *(const short8*)&Bs[rb * 32 + ((quad ^ ((rb >> 2) & 3)) << 3)];
      acc[0][nt] = __builtin_amdgcn_mfma_f32_16x16x32_bf16(afr0, bfr, acc[0][nt], 0, 0, 0);
      acc[1][nt] = __builtin_amdgcn_mfma_f32_16x16x32_bf16(afr1, bfr, acc[1][nt], 0, 0, 0);
    }
    __syncthreads();
  }
  const int head = bn >> 6;
  const int Hmul = Nfull >> 6;
  float vs[2][4] = {};
  float vd[2][4] = {};
#pragma unroll
  for (int nt = 0; nt < 4; ++nt) {
    const float asv = a_s[head * 64 + nt * 16 + l16];
    const float adv = a_d[head * 64 + nt * 16 + l16];
#pragma unroll
    for (int mt = 0; mt < 2; ++mt)
#pragma unroll
      for (int reg = 0; reg < 4; ++reg) {
        unsigned short c = f2bf(acc[mt][nt][reg]);
        int r = bm + w * 32 + mt * 16 + quad * 4 + reg;
        if (r < NN) Cb[(size_t)r * Nfull + bn + nt * 16 + l16] = c;
        float hv = bf2f(c);
        vs[mt][reg] += hv * asv;
        vd[mt][reg] += hv * adv;
      }
  }
#pragma unroll
  for (int off = 1; off < 16; off <<= 1) {
#pragma unroll
    for (int mt = 0; mt < 2; ++mt)
#pragma unroll
      for (int reg = 0; reg < 4; ++reg) {
        vs[mt][reg] += __shfl_xor(vs[mt][reg], off, 64);
        vd[mt][reg] += __shfl_xor(vd[mt][reg], off, 64);
      }
  }
  if (l16 == 0) {
#pragma unroll
    for (int mt = 0; mt < 2; ++mt)
#pragma unroll
      for (int reg = 0; reg < 4; ++reg) {
        int r = bm + w * 32 + mt * 16 + quad * 4 + reg;
        if (r < NN) {
          als[(size_t)r * Hmul + head] = vs[mt][reg];
          ald[(size_t)r * Hmul + head] = vd[mt][reg];
          selfex[(size_t)r * Hmul + head] = __expf(leaky(vs[mt][reg] + vd[mt][reg]));
        }
      }
  }
}

// ================= CSR build (topology is layer-invariant) ==================
__global__ __launch_bounds__(256) void hist_k(const int* __restrict__ ei, int* deg) {
  int i = blockIdx.x * 256 + threadIdx.x;
  if (i < EE) atomicAdd(&deg[ei[EE + i]], 1);
}

__global__ __launch_bounds__(256) void scan1_k(const int* __restrict__ deg,
                                               int* __restrict__ incl,
                                               int* __restrict__ partial) {
  __shared__ int s[256];
  int t = threadIdx.x;
  int i = blockIdx.x * 256 + t;
  int v = (i < NN) ? deg[i] : 0;
  s[t] = v;
  __syncthreads();
  for (int off = 1; off < 256; off <<= 1) {
    int u = (t >= off) ? s[t - off] : 0;
    __syncthreads();
    s[t] += u;
    __syncthreads();
  }
  if (i < NN) incl[i] = s[t];
  if (t == 255) partial[blockIdx.x] = s[255];
}

// merged scan2+scan3: every block redoes the tiny 196-entry partial scan
__global__ __launch_bounds__(256) void scan23_k(const int* __restrict__ deg,
                                                const int* __restrict__ incl,
                                                const int* __restrict__ partial,
                                                int* __restrict__ rowptr,
                                                int* __restrict__ cursor) {
  __shared__ int s[256];
  __shared__ int ex[256];
  int t = threadIdx.x;
  int v = (t < NB) ? partial[t] : 0;
  s[t] = v;
  __syncthreads();
  for (int off = 1; off < 256; off <<= 1) {
    int u = (t >= off) ? s[t - off] : 0;
    __syncthreads();
    s[t] += u;
    __syncthreads();
  }
  ex[t] = s[t] - v;  // exclusive
  __syncthreads();
  int base = ex[blockIdx.x];
  int i = blockIdx.x * 256 + t;
  if (i < NN) {
    int r = base + incl[i] - deg[i];
    rowptr[i] = r;
    cursor[i] = r;
  }
}

__global__ __launch_bounds__(256) void scatter_k(const int* __restrict__ ei,
                                                 int* __restrict__ cursor,
                                                 int* __restrict__ csr_src) {
  int i = blockIdx.x * 256 + threadIdx.x;
  if (i >= EE) return;
  int d = ei[EE + i];
  int p = atomicAdd(&cursor[d], 1);
  csr_src[p] = ei[i];
}

// ====== gather-aggregate, inline alpha + inline den-sum, H=4 (round-12) =====
__global__ __launch_bounds__(256) void aggr4c_k(const int* __restrict__ rowptr,
                                                const int* __restrict__ deg,
                                                const int* __restrict__ csr_src,
                                                const float* __restrict__ als,
                                                const float* __restrict__ ald,
                                                const float* __restrict__ selfex,
                                                const uint4* __restrict__ hb4,
                                                const float* __restrict__ bias,
                                                uint4* __restrict__ out4) {
  const int dst = blockIdx.x * 4 + (threadIdx.x >> 6);
  const int lane = threadIdx.x & 63;
  const int slot = lane >> 4;
  const int l16 = lane & 15;
  const int head = l16 >> 2;
  const int rs = rowptr[dst];
  const int dg = deg[dst];
  const float aldv = ald[dst * 4 + head];

  float acc[16] = {};
  float dsum = 0.f;
  if (slot == 0) {  // self-loop (unnormalized)
    float a = selfex[dst * 4 + head];
    dsum += a;
    uint4 v0 = hb4[(size_t)dst * 32 + l16 * 2];
    uint4 v1 = hb4[(size_t)dst * 32 + l16 * 2 + 1];
    accum8(a, v0, acc);
    accum8(a, v1, acc + 8);
  }
  int j = slot;
  for (; j + 4 < dg; j += 8) {
    int s0 = csr_src[rs + j];
    int s1 = csr_src[rs + j + 4];
    float e0 = als[s0 * 4 + head];
    float e1 = als[s1 * 4 + head];
    uint4 va0 = hb4[(size_t)s0 * 32 + l16 * 2];
    uint4 vb0 = hb4[(size_t)s0 * 32 + l16 * 2 + 1];
    uint4 va1 = hb4[(size_t)s1 * 32 + l16 * 2];
    uint4 vb1 = hb4[(size_t)s1 * 32 + l16 * 2 + 1];
    float a0 = __expf(leaky(e0 + aldv));
    float a1 = __expf(leaky(e1 + aldv));
    dsum += a0 + a1;
    accum8(a0, va0, acc);
    accum8(a0, vb0, acc + 8);
    accum8(a1, va1, acc);
    accum8(a1, vb1, acc + 8);
  }
  for (; j < dg; j += 4) {
    int s0 = csr_src[rs + j];
    float e0 = als[s0 * 4 + head];
    uint4 va0 = hb4[(size_t)s0 * 32 + l16 * 2];
    uint4 vb0 = hb4[(size_t)s0 * 32 + l16 * 2 + 1];
    float a0 = __expf(leaky(e0 + aldv));
    dsum += a0;
    accum8(a0, va0, acc);
    accum8(a0, vb0, acc + 8);
  }
#pragma unroll
  for (int k = 0; k < 16; ++k) {
    acc[k] += __shfl_xor(acc[k], 16, 64);
    acc[k] += __shfl_xor(acc[k], 32, 64);
  }
  dsum += __shfl_xor(dsum, 16, 64);
  dsum += __shfl_xor(dsum, 32, 64);
  if (slot == 0) {  // channels [l16*16, l16*16+16), relu (both H=4 layers)
    const float inv = 1.f / (dsum + 1e-16f);
    const float* bz = bias + l16 * 16;
    uint4 o0, o1;
    float c0, c1;
    c0 = fmaxf(acc[0] * inv + bz[0], 0.f);   c1 = fmaxf(acc[1] * inv + bz[1], 0.f);
    o0.x = ((unsigned int)f2bf(c1) << 16) | f2bf(c0);
    c0 = fmaxf(acc[2] * inv + bz[2], 0.f);   c1 = fmaxf(acc[3] * inv + bz[3], 0.f);
    o0.y = ((unsigned int)f2bf(c1) << 16) | f2bf(c0);
    c0 = fmaxf(acc[4] * inv + bz[4], 0.f);   c1 = fmaxf(acc[5] * inv + bz[5], 0.f);
    o0.z = ((unsigned int)f2bf(c1) << 16) | f2bf(c0);
    c0 = fmaxf(acc[6] * inv + bz[6], 0.f);   c1 = fmaxf(acc[7] * inv + bz[7], 0.f);
    o0.w = ((unsigned int)f2bf(c1) << 16) | f2bf(c0);
    c0 = fmaxf(acc[8] * inv + bz[8], 0.f);   c1 = fmaxf(acc[9] * inv + bz[9], 0.f);
    o1.x = ((unsigned int)f2bf(c1) << 16) | f2bf(c0);
    c0 = fmaxf(acc[10] * inv + bz[10], 0.f); c1 = fmaxf(acc[11] * inv + bz[11], 0.f);
    o1.y = ((unsigned int)f2bf(c1) << 16) | f2bf(c0);
    c0 = fmaxf(acc[12] * inv + bz[12], 0.f); c1 = fmaxf(acc[13] * inv + bz[13], 0.f);
    o1.z = ((unsigned int)f2bf(c1) << 16) | f2bf(c0);
    c0 = fmaxf(acc[14] * inv + bz[14], 0.f); c1 = fmaxf(acc[15] * inv + bz[15], 0.f);
    o1.w = ((unsigned int)f2bf(c1) << 16) | f2bf(c0);
    out4[(size_t)dst * 32 + l16 * 2] = o0;
    out4[(size_t)dst * 32 + l16 * 2 + 1] = o1;
  }
}

// ====== gather-aggregate, inline alpha + den-sum, H=1 (round-12) ============
__global__ __launch_bounds__(256) void aggr1c_k(const int* __restrict__ rowptr,
                                                const int* __restrict__ deg,
                                                const int* __restrict__ csr_src,
                                                const float* __restrict__ als,
                                                const float* __restrict__ ald,
                                                const float* __restrict__ selfex,
                                                const uint4* __restrict__ hb4,
                                                const float* __restrict__ bias,
                                                float* __restrict__ out) {
  const int dst = blockIdx.x * 4 + (threadIdx.x >> 6);
  const int lane = threadIdx.x & 63;
  const int slot = lane >> 3;
  const int c8 = lane & 7;
  const int rs = rowptr[dst];
  const int dg = deg[dst];
  const float aldv = ald[dst];

  float acc[8] = {};
  float dsum = 0.f;
  if (slot == 0) {
    float a = selfex[dst];
    dsum += a;
    uint4 v = hb4[(size_t)dst * 8 + c8];
    accum8(a, v, acc);
  }
  for (int j = slot; j < dg; j += 8) {
    int s = csr_src[rs + j];
    float e = als[s];
    uint4 v = hb4[(size_t)s * 8 + c8];
    float a = __expf(leaky(e + aldv));
    dsum += a;
    accum8(a, v, acc);
  }
#pragma unroll
  for (int k = 0; k < 8; ++k) {
    acc[k] += __shfl_xor(acc[k], 8, 64);
    acc[k] += __shfl_xor(acc[k], 16, 64);
    acc[k] += __shfl_xor(acc[k], 32, 64);
  }
  dsum += __shfl_xor(dsum, 8, 64);
  dsum += __shfl_xor(dsum, 16, 64);
  dsum += __shfl_xor(dsum, 32, 64);
  if (slot == 0) {  // no relu on layer 2; fp32 out
    const float inv = 1.f / (dsum + 1e-16f);
    const float4 bz0 = *(const float4*)(bias + c8 * 8);
    const float4 bz1 = *(const float4*)(bias + c8 * 8 + 4);
    float4 o0 = make_float4(acc[0] * inv + bz0.x, acc[1] * inv + bz0.y,
                            acc[2] * inv + bz0.z, acc[3] * inv + bz0.w);
    float4 o1 = make_float4(acc[4] * inv + bz1.x, acc[5] * inv + bz1.y,
                            acc[6] * inv + bz1.z, acc[7] * inv + bz1.w);
    *(float4*)(out + (size_t)dst * 64 + c8 * 8) = o0;
    *(float4*)(out + (size_t)dst * 64 + c8 * 8 + 4) = o1;
  }
}

// ---- fused prep: x cast + 3 weight transposes + deg zero + g zero ----------
__global__ __launch_bounds__(256) void prep_k(const float2* __restrict__ x2,
                                              unsigned int* __restrict__ xb_u,
                                              const float* __restrict__ W0,
                                              unsigned short* __restrict__ W0t,
                                              const float* __restrict__ W1,
                                              unsigned short* __restrict__ W1t,
                                              const float* __restrict__ W2,
                                              unsigned short* __restrict__ W2t,
                                              int* __restrict__ deg,
                                              float* __restrict__ g) {
  int bid = blockIdx.x;
  int tid = threadIdx.x;
  if (bid < 12500) {  // castx: NN*128/2 = 3.2M uints
    int i = bid * 256 + tid;
    float2 v = x2[i];
    xb_u[i] = ((unsigned int)f2bf(v.y) << 16) | f2bf(v.x);
    return;
  }
  if (bid < 12948) {  // weight transposes (448 blocks = 114688 threads exact)
    int r = (bid - 12500) * 256 + tid;
    if (r < 32768) {            // W0t[256][128] <- W0[128][256]
      int n = r >> 7, k = r & 127;
      W0t[n * 128 + k] = f2bf(W0[k * 256 + n]);
    } else if (r < 98304) {     // W1t[256][256] <- W1[256][256]
      int rr = r - 32768;
      int n = rr >> 8, k = rr & 255;
      W1t[n * 256 + k] = f2bf(W1[k * 256 + n]);
    } else {                    // W2t[64][256] <- W2[256][64]
      int rr = r - 98304;
      int n = rr >> 8, k = rr & 255;
      W2t[n * 256 + k] = f2bf(W2[k * 64 + n]);
    }
    return;
  }
  if (bid < 13144) {  // deg zero (196 blocks)
    int i = (bid - 12948) * 256 + tid;
    if (i < NN) deg[i] = 0;
    return;
  }
  if (tid < 68) g[tid] = 0.f;  // g sums + counter
}

// ---- colsum + fused head: last block computes the final [1,64] output ------
__global__ __launch_bounds__(256) void colsum_head_k(const float* __restrict__ h2,
                                                     float* __restrict__ g,
                                                     unsigned int* __restrict__ cnt,
                                                     const float* __restrict__ hw,
                                                     const float* __restrict__ hb,
                                                     float* __restrict__ out) {
  __shared__ float s[256];
  __shared__ float sg[64];
  __shared__ unsigned int sdone;
  int tid = threadIdx.x;
  int c = tid & 63, rg = tid >> 6;
  float acc = 0.f;
  for (int n = blockIdx.x * 4 + rg; n < NN; n += gridDim.x * 4)
    acc += h2[n * 64 + c];
  s[tid] = acc;
  __syncthreads();
  if (tid < 64) atomicAdd(&g[c], s[c] + s[64 + c] + s[128 + c] + s[192 + c]);
  __threadfence();
  __syncthreads();
  if (tid == 0) sdone = atomicAdd(cnt, 1);
  __syncthreads();
  if (sdone != gridDim.x - 1) return;
  if (tid < 64) sg[tid] = atomicAdd(&g[tid], 0.f);  // coherent read
  __syncthreads();
  if (tid < 64) {
    const float invN = 1.0f / (float)NN;
    float a2 = hb[tid];
#pragma unroll 8
    for (int cc = 0; cc < 64; ++cc) a2 += sg[cc] * invN * hw[cc * 64 + tid];
    out[tid] = a2;
  }
}

extern "C" void kernel_launch(void* const* d_in, const int* in_sizes, int n_in,
                              void* d_out, int out_size, void* d_ws, size_t ws_size,
                              hipStream_t stream) {
  const float* x   = (const float*)d_in[0];
  const int*   ei  = (const int*)d_in[1];
  const float* W0  = (const float*)d_in[2];
  const float* a0s = (const float*)d_in[3];
  const float* a0d = (const float*)d_in[4];
  const float* b0  = (const float*)d_in[5];
  const float* W1  = (const float*)d_in[6];
  const float* a1s = (const float*)d_in[7];
  const float* a1d = (const float*)d_in[8];
  const float* b1  = (const float*)d_in[9];
  const float* W2  = (const float*)d_in[10];
  const float* a2s = (const float*)d_in[11];
  const float* a2d = (const float*)d_in[12];
  const float* b2  = (const float*)d_in[13];
  const float* hw  = (const float*)d_in[14];
  const float* hb  = (const float*)d_in[15];
  float* out = (float*)d_out;

  char* w = (char*)d_ws;
  unsigned short* xb   = (unsigned short*)w; w += (size_t)NN * 128 * 2;
  unsigned short* bufG = (unsigned short*)w; w += (size_t)NN * 256 * 2;
  unsigned short* bufA = (unsigned short*)w; w += (size_t)NN * 256 * 2;
  float* bufF = (float*)w;                   w += (size_t)NN * 64 * 4;
  unsigned short* W0t = (unsigned short*)w;  w += 256 * 128 * 2;
  unsigned short* W1t = (unsigned short*)w;  w += 256 * 256 * 2;
  unsigned short* W2t = (unsigned short*)w;  w += 64 * 256 * 2;
  float* als  = (float*)w;    w += (size_t)NN * 4 * 4;
  float* ald  = (float*)w;    w += (size_t)NN * 4 * 4;
  float* sfx  = (float*)w;    w += (size_t)NN * 4 * 4;
  int* deg     = (int*)w;     w += (size_t)NN * 4;
  int* rowptr  = (int*)w;     w += (size_t)NN * 4;
  int* cursor  = (int*)w;     w += (size_t)NN * 4;
  int* incl    = (int*)w;     w += (size_t)NN * 4;
  int* partial = (int*)w;     w += 256 * 4;
  int* csr_src = (int*)w;     w += (size_t)EE * 4;
  float* g    = (float*)w;    w += 256;           // g[0..63] sums; cnt at g+64

  // ---- prep (also zeroes deg and g) must precede hist ----
  prep_k<<<13145, 256, 0, stream>>>((const float2*)x, (unsigned int*)xb,
                                    W0, W0t, W1, W1t, W2, W2t, deg, g);

  // ---- CSR build (shared by all 3 layers) ----
  hist_k<<<(EE + 255) / 256, 256, 0, stream>>>(ei, deg);
  scan1_k<<<NB, 256, 0, stream>>>(deg, incl, partial);
  scan23_k<<<NB, 256, 0, stream>>>(deg, incl, partial, rowptr, cursor);
  scatter_k<<<(EE + 255) / 256, 256, 0, stream>>>(ei, cursor, csr_src);

  const int GX = (NN + 127) / 128;
  const int GA = NN / 4;   // 12500 exact

  auto layer4 = [&](const unsigned short* in, int K, const unsigned short* Wt,
                    const float* a_s, const float* a_d, const float* bias,
                    unsigned short* hbuf, unsigned short* obuf) {
    gemm_bf16_k<<<dim3(GX, 4), 256, 0, stream>>>(in, Wt, hbuf, K, 256,
                                                 a_s, a_d, als, ald, sfx);
    aggr4c_k<<<GA, 256, 0, stream>>>(rowptr, deg, csr_src, als, ald, sfx,
                                     (const uint4*)hbuf, bias, (uint4*)obuf);
  };

  // layers 0 and 1 (H=4)
  layer4(xb, 128, W0t, a0s, a0d, b0, bufG, bufA);
  layer4(bufA, 256, W1t, a1s, a1d, b1, bufG, bufA);

  // layer 2 (H=1)
  gemm_bf16_k<<<dim3(GX, 1), 256, 0, stream>>>(bufA, W2t, bufG, 256, 64,
                                               a2s, a2d, als, ald, sfx);
  aggr1c_k<<<GA, 256, 0, stream>>>(rowptr, deg, csr_src, als, ald, sfx,
                                   (const uint4*)bufG, b2, bufF);

  // ---- mean + head (g zeroed by prep_k) ----
  colsum_head_k<<<256, 256, 0, stream>>>(bufF, g, (unsigned int*)(g + 64), hw, hb, out);
}